// Round 6
// baseline (233.449 us; speedup 1.0000x reference)
//
#include <hip/hip_runtime.h>
#include <math.h>

#define N_NODES 30000
#define N_EDGES 150000
#define IN_F 16
#define H_F 32
#define C_F 10
// K = IN*H = 512 hidden units in the edge MLP; 513 piecewise-linear intervals.
// theta(a) = a*A_m + B2_m on interval m; tables TRANSPOSED as A_t[m][o][i]
// (o=0..31, i=0..15) so lane o reads its 16 weights as 4 float4s.
// Edges counting-sorted by m (padded bins!) so consecutive warps hit the same
// table rows -> L1-resident instead of 600 MB of random L2 reads.

// ---------------------------------------------------------------------------
// K0: zero summed[N*32] + deg[N] + histp[513*16] (contiguous), float4.
// ---------------------------------------------------------------------------
__global__ void k0_zero(float4* __restrict__ p, int n4) {
    int i = blockIdx.x * blockDim.x + threadIdx.x;
    int stride = gridDim.x * blockDim.x;
    float4 z = make_float4(0.f, 0.f, 0.f, 0.f);
    for (; i < n4; i += stride) p[i] = z;
}

// ---------------------------------------------------------------------------
// K1: breakpoints t_k = -b1_k/W1_k, O(n^2) rank sort (no barriers in loop).
// ---------------------------------------------------------------------------
__global__ void k1_rank(const float* __restrict__ W1, const float* __restrict__ b1,
                        float* __restrict__ tsort, int* __restrict__ ksort) {
    __shared__ float st[512];
    int tid = threadIdx.x;
    float w = W1[tid], b = b1[tid];
    float t = (w != 0.0f) ? (-b / w) : 3.0e38f;
    st[tid] = t;
    __syncthreads();
    int rank = 0;
#pragma unroll 8
    for (int j = 0; j < 512; ++j) {
        float tj = st[j];
        rank += (tj < t || (tj == t && j < tid)) ? 1 : 0;
    }
    tsort[rank] = t;
    ksort[rank] = tid;
}

// ---------------------------------------------------------------------------
// KB1: per-edge prep: in-degree histogram, interval me[e] (binary search),
// PADDED interval histogram (one counter per 64B line).
// ---------------------------------------------------------------------------
__global__ void kb1_prep(const int* __restrict__ ei, const float* __restrict__ ea,
                         const float* __restrict__ tsort,
                         int* __restrict__ deg, int* __restrict__ histp,
                         int* __restrict__ me) {
    __shared__ float ts[512];
    for (int i = threadIdx.x; i < 512; i += blockDim.x) ts[i] = tsort[i];
    __syncthreads();
    int e = blockIdx.x * blockDim.x + threadIdx.x;
    if (e >= N_EDGES) return;
    atomicAdd(&deg[ei[N_EDGES + e]], 1);
    float a = ea[e];
    int lo = 0, hi = 512;
    while (lo < hi) {
        int mid = (lo + hi) >> 1;
        if (ts[mid] < a) lo = mid + 1; else hi = mid;
    }
    me[e] = lo;
    atomicAdd(&histp[lo * 16], 1);
}

// ---------------------------------------------------------------------------
// S_SCAN: single block, 1024 threads.
// Phase A: exclusive scan of deg[30000] -> offs/cur.
// Phase B: exclusive scan of histp (stride 16) -> mcur (stride 16).
// ---------------------------------------------------------------------------
__global__ void s_scan(const int* __restrict__ deg, const int* __restrict__ histp,
                       int* __restrict__ offs, int* __restrict__ cur,
                       int* __restrict__ mcur) {
    __shared__ int part[1024];
    int t = threadIdx.x;
    int base = t * 30;
    int loc[30];
    int s = 0;
#pragma unroll
    for (int i = 0; i < 30; ++i) {
        int idx = base + i;
        int v = (idx < N_NODES) ? deg[idx] : 0;
        loc[i] = v;
        s += v;
    }
    part[t] = s;
    __syncthreads();
    for (int off = 1; off < 1024; off <<= 1) {
        int v = part[t];
        int add = (t >= off) ? part[t - off] : 0;
        __syncthreads();
        part[t] = v + add;
        __syncthreads();
    }
    int run = (t > 0) ? part[t - 1] : 0;
#pragma unroll
    for (int i = 0; i < 30; ++i) {
        int idx = base + i;
        if (idx < N_NODES) { offs[idx] = run; cur[idx] = run; }
        run += loc[i];
    }
    if (t == 1023) offs[N_NODES] = run;
    __syncthreads();
    // phase B: interval bins (padded stride 16)
    int v = (t < 513) ? histp[t * 16] : 0;
    part[t] = v;
    __syncthreads();
    for (int off = 1; off < 1024; off <<= 1) {
        int x = part[t];
        int add = (t >= off) ? part[t - off] : 0;
        __syncthreads();
        part[t] = x + add;
        __syncthreads();
    }
    if (t < 513) mcur[t * 16] = part[t] - v;  // exclusive prefix
}

// ---------------------------------------------------------------------------
// KB3: fill dst-CSR (ssrc) + m-sorted packed edge records epk[(s,d,m,a)].
// Padded mcur bins -> no per-line atomic serialization.
// ---------------------------------------------------------------------------
__global__ void kb3_fill(const int* __restrict__ ei, const float* __restrict__ ea,
                         const int* __restrict__ me,
                         int* __restrict__ cur, int* __restrict__ mcur,
                         int* __restrict__ ssrc, int4* __restrict__ epk) {
    int e = blockIdx.x * blockDim.x + threadIdx.x;
    if (e >= N_EDGES) return;
    int s = ei[e], d = ei[N_EDGES + e];
    int slot = atomicAdd(&cur[d], 1);
    ssrc[slot] = s;
    int m = me[e];
    int slot2 = atomicAdd(&mcur[m * 16], 1);
    epk[slot2] = make_int4(s, d, m, __float_as_int(ea[e]));
}

// ---------------------------------------------------------------------------
// P1: per-chunk partial sums over 32 chunks of 16 ranks (linear j layout).
// ---------------------------------------------------------------------------
__global__ void p1_chunks(const float* __restrict__ W1, const float* __restrict__ b1,
                          const float* __restrict__ W2, const int* __restrict__ ksort,
                          float* __restrict__ PbA, float* __restrict__ PbB,
                          float* __restrict__ SA, float* __restrict__ SB) {
    int c = blockIdx.x & 31;
    int jc = blockIdx.x >> 5;
    int j = jc * 256 + threadIdx.x;
    float ba = 0.0f, bb = 0.0f, sa = 0.0f, sb = 0.0f;
#pragma unroll 4
    for (int s = 0; s < 16; ++s) {
        int k = c * 16 + s;
        float w = W1[k], b = b1[k];
        bool act = (w < 0.0f) || (w == 0.0f && b > 0.0f);
        if (act) {
            float w2 = W2[k * 512 + j];
            ba = fmaf(w, w2, ba);
            bb = fmaf(b, w2, bb);
        }
        int kr = ksort[c * 16 + s];
        float wr = W1[kr], br = b1[kr];
        float sgn = (wr > 0.0f) ? 1.0f : ((wr < 0.0f) ? -1.0f : 0.0f);
        float w2r = W2[kr * 512 + j];
        sa = fmaf(sgn * wr, w2r, sa);
        sb = fmaf(sgn * br, w2r, sb);
    }
    PbA[c * 512 + j] = ba; PbB[c * 512 + j] = bb;
    SA[c * 512 + j] = sa;  SB[c * 512 + j] = sb;
}

// ---------------------------------------------------------------------------
// P3S: fused scan + emit with TRANSPOSED writes A[m*512 + (j&31)*16 + (j>>5)].
// ---------------------------------------------------------------------------
__global__ void p3s_emit(const float* __restrict__ W1, const float* __restrict__ b1,
                         const float* __restrict__ b2, const float* __restrict__ W2,
                         const int* __restrict__ ksort,
                         const float* __restrict__ PbA, const float* __restrict__ PbB,
                         const float* __restrict__ SA, const float* __restrict__ SB,
                         float* __restrict__ A, float* __restrict__ B2t) {
    int c = blockIdx.x & 31;
    int jc = blockIdx.x >> 5;
    int j = jc * 256 + threadIdx.x;
    float runA = 0.0f, runB = 0.0f;
#pragma unroll
    for (int c2 = 0; c2 < 32; ++c2) {
        runA += PbA[c2 * 512 + j];
        runB += PbB[c2 * 512 + j];
        if (c2 < c) { runA += SA[c2 * 512 + j]; runB += SB[c2 * 512 + j]; }
    }
    float bb2 = b2[j];
    int jt = ((j & 31) << 4) | (j >> 5);   // transposed offset within row
#pragma unroll 4
    for (int s = 0; s < 16; ++s) {
        int m = c * 16 + s;
        A[m * 512 + jt]   = runA;
        B2t[m * 512 + jt] = runB + bb2;
        int k = ksort[m];
        float w = W1[k], b = b1[k];
        float sgn = (w > 0.0f) ? 1.0f : ((w < 0.0f) ? -1.0f : 0.0f);
        float w2 = W2[k * 512 + j];
        runA = fmaf(sgn * w, w2, runA);
        runB = fmaf(sgn * b, w2, runB);
    }
    if (c == 31) {
        A[512 * 512 + jt]   = runA;
        B2t[512 * 512 + jt] = runB + bb2;
    }
}

// ---------------------------------------------------------------------------
// K3S: m-sorted per-edge message. 32 lanes/edge. Edge record = one int4
// (coalesced). Consecutive warps share m -> table rows served from L1.
// Lane o: 4+4 float4 loads of its own 64B lines; shfl-broadcast x; atomic
// scatter to summed[dst*32+o].
// ---------------------------------------------------------------------------
__global__ void __launch_bounds__(256) k3s(
        const float* __restrict__ x, const int4* __restrict__ epk,
        const float* __restrict__ A, const float* __restrict__ B2t,
        float* __restrict__ summed) {
    int gid = blockIdx.x * blockDim.x + threadIdx.x;
    int lane = gid & 31;
    int idx = gid >> 5;
    if (idx >= N_EDGES) return;
    int4 pk = epk[idx];
    int s = pk.x, d = pk.y, m = pk.z;
    float a = __int_as_float(pk.w);
    const float4* Ar = (const float4*)(A   + m * 512 + lane * 16);
    const float4* Br = (const float4*)(B2t + m * 512 + lane * 16);
    float4 a0 = Ar[0], a1 = Ar[1], a2 = Ar[2], a3 = Ar[3];
    float4 b0 = Br[0], b1 = Br[1], b2 = Br[2], b3 = Br[3];
    float xv = (lane < 16) ? x[s * 16 + lane] : 0.0f;
    float xa = 0.0f, xb = 0.0f;
    float xi;
    xi = __shfl(xv,  0, 32); xa = fmaf(xi, a0.x, xa); xb = fmaf(xi, b0.x, xb);
    xi = __shfl(xv,  1, 32); xa = fmaf(xi, a0.y, xa); xb = fmaf(xi, b0.y, xb);
    xi = __shfl(xv,  2, 32); xa = fmaf(xi, a0.z, xa); xb = fmaf(xi, b0.z, xb);
    xi = __shfl(xv,  3, 32); xa = fmaf(xi, a0.w, xa); xb = fmaf(xi, b0.w, xb);
    xi = __shfl(xv,  4, 32); xa = fmaf(xi, a1.x, xa); xb = fmaf(xi, b1.x, xb);
    xi = __shfl(xv,  5, 32); xa = fmaf(xi, a1.y, xa); xb = fmaf(xi, b1.y, xb);
    xi = __shfl(xv,  6, 32); xa = fmaf(xi, a1.z, xa); xb = fmaf(xi, b1.z, xb);
    xi = __shfl(xv,  7, 32); xa = fmaf(xi, a1.w, xa); xb = fmaf(xi, b1.w, xb);
    xi = __shfl(xv,  8, 32); xa = fmaf(xi, a2.x, xa); xb = fmaf(xi, b2.x, xb);
    xi = __shfl(xv,  9, 32); xa = fmaf(xi, a2.y, xa); xb = fmaf(xi, b2.y, xb);
    xi = __shfl(xv, 10, 32); xa = fmaf(xi, a2.z, xa); xb = fmaf(xi, b2.z, xb);
    xi = __shfl(xv, 11, 32); xa = fmaf(xi, a2.w, xa); xb = fmaf(xi, b2.w, xb);
    xi = __shfl(xv, 12, 32); xa = fmaf(xi, a3.x, xa); xb = fmaf(xi, b3.x, xb);
    xi = __shfl(xv, 13, 32); xa = fmaf(xi, a3.y, xa); xb = fmaf(xi, b3.y, xb);
    xi = __shfl(xv, 14, 32); xa = fmaf(xi, a3.z, xa); xb = fmaf(xi, b3.z, xb);
    xi = __shfl(xv, 15, 32); xa = fmaf(xi, a3.w, xa); xb = fmaf(xi, b3.w, xb);
    atomicAdd(&summed[d * 32 + lane], fmaf(a, xa, xb));
}

// ---------------------------------------------------------------------------
// K4: per-node: aggr = summed/max(cnt,1); h1 = relu(aggr + x@root + bias1);
// xw12[n][0..9] = h1@Wg; xw12[n][10] = rsqrt(indeg+1); [11] = 0.
// ---------------------------------------------------------------------------
__global__ void k4_nodes(const float* __restrict__ x, const float* __restrict__ summed,
                         const int* __restrict__ offs,
                         const float* __restrict__ root, const float* __restrict__ bias1,
                         const float* __restrict__ Wg,
                         float* __restrict__ xw12) {
    __shared__ float sroot[512], sb1[32], swg[320];
    for (int i = threadIdx.x; i < 512; i += blockDim.x) sroot[i] = root[i];
    for (int i = threadIdx.x; i < 32; i += blockDim.x) sb1[i] = bias1[i];
    for (int i = threadIdx.x; i < 320; i += blockDim.x) swg[i] = Wg[i];
    __syncthreads();
    int n = blockIdx.x * blockDim.x + threadIdx.x;
    if (n >= N_NODES) return;
    float c = (float)(offs[n + 1] - offs[n]);
    float inv = 1.0f / fmaxf(c, 1.0f);
    const float4* xp = (const float4*)(x + n * 16);
    float xr[16];
#pragma unroll
    for (int q = 0; q < 4; ++q) {
        float4 v = xp[q];
        xr[q * 4 + 0] = v.x; xr[q * 4 + 1] = v.y;
        xr[q * 4 + 2] = v.z; xr[q * 4 + 3] = v.w;
    }
    const float4* sp = (const float4*)(summed + n * 32);
    float sm[32];
#pragma unroll
    for (int q = 0; q < 8; ++q) {
        float4 v = sp[q];
        sm[q * 4 + 0] = v.x; sm[q * 4 + 1] = v.y;
        sm[q * 4 + 2] = v.z; sm[q * 4 + 3] = v.w;
    }
    float acc[10];
#pragma unroll
    for (int cc = 0; cc < 10; ++cc) acc[cc] = 0.0f;
#pragma unroll
    for (int o = 0; o < 32; ++o) {
        float h = sm[o] * inv + sb1[o];
#pragma unroll
        for (int i = 0; i < 16; ++i) h = fmaf(xr[i], sroot[i * 32 + o], h);
        h = fmaxf(h, 0.0f);
#pragma unroll
        for (int cc = 0; cc < 10; ++cc) acc[cc] = fmaf(h, swg[o * 10 + cc], acc[cc]);
    }
    float4* op = (float4*)(xw12 + n * 12);
    op[0] = make_float4(acc[0], acc[1], acc[2], acc[3]);
    op[1] = make_float4(acc[4], acc[5], acc[6], acc[7]);
    op[2] = make_float4(acc[8], acc[9], rsqrtf(c + 1.0f), 0.0f);
}

// ---------------------------------------------------------------------------
// K56: fused GCN gather + self-loop + bias + log_softmax -> d_out.
// ---------------------------------------------------------------------------
__global__ void k56_final(const int* __restrict__ offs, const int* __restrict__ ssrc,
                          const float* __restrict__ xw12,
                          const float* __restrict__ bg, float* __restrict__ out) {
    __shared__ float sbg[16];
    if (threadIdx.x < 10) sbg[threadIdx.x] = bg[threadIdx.x];
    __syncthreads();
    int n = blockIdx.x * blockDim.x + threadIdx.x;
    if (n >= N_NODES) return;
    const float4* base = (const float4*)xw12;
    float4 r0 = base[n * 3], r1 = base[n * 3 + 1], r2 = base[n * 3 + 2];
    float dn = r2.z;
    float d2 = dn * dn;
    float acc[10];
    acc[0] = fmaf(r0.x, d2, sbg[0]); acc[1] = fmaf(r0.y, d2, sbg[1]);
    acc[2] = fmaf(r0.z, d2, sbg[2]); acc[3] = fmaf(r0.w, d2, sbg[3]);
    acc[4] = fmaf(r1.x, d2, sbg[4]); acc[5] = fmaf(r1.y, d2, sbg[5]);
    acc[6] = fmaf(r1.z, d2, sbg[6]); acc[7] = fmaf(r1.w, d2, sbg[7]);
    acc[8] = fmaf(r2.x, d2, sbg[8]); acc[9] = fmaf(r2.y, d2, sbg[9]);
    int s0 = offs[n], s1 = offs[n + 1];
    for (int sl = s0; sl < s1; ++sl) {
        int s = ssrc[sl];
        float4 q0 = base[s * 3], q1 = base[s * 3 + 1], q2 = base[s * 3 + 2];
        float nf = q2.z * dn;
        acc[0] = fmaf(q0.x, nf, acc[0]); acc[1] = fmaf(q0.y, nf, acc[1]);
        acc[2] = fmaf(q0.z, nf, acc[2]); acc[3] = fmaf(q0.w, nf, acc[3]);
        acc[4] = fmaf(q1.x, nf, acc[4]); acc[5] = fmaf(q1.y, nf, acc[5]);
        acc[6] = fmaf(q1.z, nf, acc[6]); acc[7] = fmaf(q1.w, nf, acc[7]);
        acc[8] = fmaf(q2.x, nf, acc[8]); acc[9] = fmaf(q2.y, nf, acc[9]);
    }
    float mx = -1e30f;
#pragma unroll
    for (int c = 0; c < 10; ++c) mx = fmaxf(mx, acc[c]);
    float se = 0.0f;
#pragma unroll
    for (int c = 0; c < 10; ++c) se += expf(acc[c] - mx);
    float lse = logf(se) + mx;
#pragma unroll
    for (int c = 0; c < 10; ++c) out[n * 10 + c] = acc[c] - lse;
}

// ---------------------------------------------------------------------------
extern "C" void kernel_launch(void* const* d_in, const int* in_sizes, int n_in,
                              void* d_out, int out_size, void* d_ws, size_t ws_size,
                              hipStream_t stream) {
    const float* x     = (const float*)d_in[0];
    const float* ea    = (const float*)d_in[1];
    const float* W1    = (const float*)d_in[2];
    const float* b1    = (const float*)d_in[3];
    const float* W2    = (const float*)d_in[4];
    const float* b2    = (const float*)d_in[5];
    const float* root  = (const float*)d_in[6];
    const float* bias1 = (const float*)d_in[7];
    const float* Wg    = (const float*)d_in[8];
    const float* bg    = (const float*)d_in[9];
    const int*   ei    = (const int*)d_in[10];
    float* out = (float*)d_out;

    // workspace layout (4-byte units; every segment size is a multiple of 4
    // so all float4/int4 segments stay 16B-aligned)
    float* A      = (float*)d_ws;                    // 513*512
    float* B2t    = A + 513 * 512;                   // 513*512
    float* tsort  = B2t + 513 * 512;                 // 512
    int*   ksort  = (int*)(tsort + 512);             // 512
    int4*  epk    = (int4*)(ksort + 512);            // E int4 (16B aligned)
    float* summed = (float*)(epk + N_EDGES);         // N*32   <- zero start
    int*   deg    = (int*)(summed + N_NODES * 32);   // N
    int*   histp  = deg + N_NODES;                   // 513*16 <- zero end
    int*   offs   = histp + 513 * 16;                // N+4
    int*   cur    = offs + N_NODES + 4;              // N
    int*   mcur   = cur + N_NODES;                   // 513*16
    int*   me     = mcur + 513 * 16;                 // E
    int*   ssrc   = me + N_EDGES;                    // E
    float* xw12   = (float*)(ssrc + N_EDGES);        // N*12 (16B aligned)
    float* PbA    = xw12 + N_NODES * 12;             // 32*512
    float* PbB    = PbA + 32 * 512;
    float* SA     = PbB + 32 * 512;
    float* SB     = SA + 32 * 512;

    int zero4 = (N_NODES * 33 + 513 * 16) / 4;       // summed+deg+histp, /4
    k0_zero<<<1024, 256, 0, stream>>>((float4*)summed, zero4);
    k1_rank<<<1, 512, 0, stream>>>(W1, b1, tsort, ksort);
    kb1_prep<<<(N_EDGES + 255) / 256, 256, 0, stream>>>(ei, ea, tsort, deg, histp, me);
    s_scan<<<1, 1024, 0, stream>>>(deg, histp, offs, cur, mcur);
    kb3_fill<<<(N_EDGES + 255) / 256, 256, 0, stream>>>(ei, ea, me, cur, mcur,
                                                        ssrc, epk);
    p1_chunks<<<64, 256, 0, stream>>>(W1, b1, W2, ksort, PbA, PbB, SA, SB);
    p3s_emit<<<64, 256, 0, stream>>>(W1, b1, b2, W2, ksort, PbA, PbB, SA, SB, A, B2t);
    k3s<<<(N_EDGES * 32 + 255) / 256, 256, 0, stream>>>(x, epk, A, B2t, summed);
    k4_nodes<<<(N_NODES + 255) / 256, 256, 0, stream>>>(x, summed, offs, root, bias1,
                                                        Wg, xw12);
    k56_final<<<(N_NODES + 255) / 256, 256, 0, stream>>>(offs, ssrc, xw12, bg, out);
}

// Round 7
// 175.130 us; speedup vs baseline: 1.3330x; 1.3330x over previous
//
#include <hip/hip_runtime.h>
#include <math.h>

#define N_NODES 30000
#define N_EDGES 150000
#define IN_F 16
#define H_F 32
#define C_F 10
// K = IN*H = 512 hidden units in the edge MLP; 513 piecewise-linear intervals.
// theta(a) = a*A_m + B2_m on interval m; tables TRANSPOSED as A_t[m][o][i]
// (o=0..31, i=0..15) so lane o reads its 16 weights as 4 float4s.
// k3 writes each edge's 32-wide message to its dst-CSR slot (plain bf16
// stores, no atomics); k4 streams contiguous slot rows per node.

// ---------------------------------------------------------------------------
// K0: zero deg[N]
// ---------------------------------------------------------------------------
__global__ void k0_zero(int* __restrict__ p, int n) {
    int i = blockIdx.x * blockDim.x + threadIdx.x;
    int stride = gridDim.x * blockDim.x;
    for (; i < n; i += stride) p[i] = 0;
}

// ---------------------------------------------------------------------------
// K1: breakpoints t_k = -b1_k/W1_k, O(n^2) rank sort (no barriers in loop).
// ---------------------------------------------------------------------------
__global__ void k1_rank(const float* __restrict__ W1, const float* __restrict__ b1,
                        float* __restrict__ tsort, int* __restrict__ ksort) {
    __shared__ float st[512];
    int tid = threadIdx.x;
    float w = W1[tid], b = b1[tid];
    float t = (w != 0.0f) ? (-b / w) : 3.0e38f;
    st[tid] = t;
    __syncthreads();
    int rank = 0;
#pragma unroll 8
    for (int j = 0; j < 512; ++j) {
        float tj = st[j];
        rank += (tj < t || (tj == t && j < tid)) ? 1 : 0;
    }
    tsort[rank] = t;
    ksort[rank] = tid;
}

// ---------------------------------------------------------------------------
// KB1: per-edge prep: in-degree histogram + interval me[e] via binary search.
// ---------------------------------------------------------------------------
__global__ void kb1_prep(const int* __restrict__ ei, const float* __restrict__ ea,
                         const float* __restrict__ tsort,
                         int* __restrict__ deg, int* __restrict__ me) {
    __shared__ float ts[512];
    for (int i = threadIdx.x; i < 512; i += blockDim.x) ts[i] = tsort[i];
    __syncthreads();
    int e = blockIdx.x * blockDim.x + threadIdx.x;
    if (e >= N_EDGES) return;
    atomicAdd(&deg[ei[N_EDGES + e]], 1);
    float a = ea[e];
    int lo = 0, hi = 512;
    while (lo < hi) {
        int mid = (lo + hi) >> 1;
        if (ts[mid] < a) lo = mid + 1; else hi = mid;
    }
    me[e] = lo;
}

// ---------------------------------------------------------------------------
// S_SCAN: single block, 1024 threads: exclusive scan of deg -> offs/cur.
// ---------------------------------------------------------------------------
__global__ void s_scan(const int* __restrict__ deg, int* __restrict__ offs,
                       int* __restrict__ cur) {
    __shared__ int part[1024];
    int t = threadIdx.x;
    int base = t * 30;
    int loc[30];
    int s = 0;
#pragma unroll
    for (int i = 0; i < 30; ++i) {
        int idx = base + i;
        int v = (idx < N_NODES) ? deg[idx] : 0;
        loc[i] = v;
        s += v;
    }
    part[t] = s;
    __syncthreads();
    for (int off = 1; off < 1024; off <<= 1) {
        int v = part[t];
        int add = (t >= off) ? part[t - off] : 0;
        __syncthreads();
        part[t] = v + add;
        __syncthreads();
    }
    int run = (t > 0) ? part[t - 1] : 0;
#pragma unroll
    for (int i = 0; i < 30; ++i) {
        int idx = base + i;
        if (idx < N_NODES) { offs[idx] = run; cur[idx] = run; }
        run += loc[i];
    }
    if (t == 1023) offs[N_NODES] = run;
}

// ---------------------------------------------------------------------------
// KB3: dst-CSR fill: slot per edge, source list, and eslot[e] for k3.
// ---------------------------------------------------------------------------
__global__ void kb3_fill(const int* __restrict__ ei, int* __restrict__ cur,
                         int* __restrict__ ssrc, int* __restrict__ eslot) {
    int e = blockIdx.x * blockDim.x + threadIdx.x;
    if (e >= N_EDGES) return;
    int s = ei[e], d = ei[N_EDGES + e];
    int slot = atomicAdd(&cur[d], 1);
    ssrc[slot] = s;
    eslot[e] = slot;
}

// ---------------------------------------------------------------------------
// P1: per-chunk partial sums over 32 chunks of 16 ranks (linear j layout).
// ---------------------------------------------------------------------------
__global__ void p1_chunks(const float* __restrict__ W1, const float* __restrict__ b1,
                          const float* __restrict__ W2, const int* __restrict__ ksort,
                          float* __restrict__ PbA, float* __restrict__ PbB,
                          float* __restrict__ SA, float* __restrict__ SB) {
    int c = blockIdx.x & 31;
    int jc = blockIdx.x >> 5;
    int j = jc * 256 + threadIdx.x;
    float ba = 0.0f, bb = 0.0f, sa = 0.0f, sb = 0.0f;
#pragma unroll 4
    for (int s = 0; s < 16; ++s) {
        int k = c * 16 + s;
        float w = W1[k], b = b1[k];
        bool act = (w < 0.0f) || (w == 0.0f && b > 0.0f);
        if (act) {
            float w2 = W2[k * 512 + j];
            ba = fmaf(w, w2, ba);
            bb = fmaf(b, w2, bb);
        }
        int kr = ksort[c * 16 + s];
        float wr = W1[kr], br = b1[kr];
        float sgn = (wr > 0.0f) ? 1.0f : ((wr < 0.0f) ? -1.0f : 0.0f);
        float w2r = W2[kr * 512 + j];
        sa = fmaf(sgn * wr, w2r, sa);
        sb = fmaf(sgn * br, w2r, sb);
    }
    PbA[c * 512 + j] = ba; PbB[c * 512 + j] = bb;
    SA[c * 512 + j] = sa;  SB[c * 512 + j] = sb;
}

// ---------------------------------------------------------------------------
// P3S: fused scan + emit with TRANSPOSED writes A[m*512 + (j&31)*16 + (j>>5)].
// ---------------------------------------------------------------------------
__global__ void p3s_emit(const float* __restrict__ W1, const float* __restrict__ b1,
                         const float* __restrict__ b2, const float* __restrict__ W2,
                         const int* __restrict__ ksort,
                         const float* __restrict__ PbA, const float* __restrict__ PbB,
                         const float* __restrict__ SA, const float* __restrict__ SB,
                         float* __restrict__ A, float* __restrict__ B2t) {
    int c = blockIdx.x & 31;
    int jc = blockIdx.x >> 5;
    int j = jc * 256 + threadIdx.x;
    float runA = 0.0f, runB = 0.0f;
#pragma unroll
    for (int c2 = 0; c2 < 32; ++c2) {
        runA += PbA[c2 * 512 + j];
        runB += PbB[c2 * 512 + j];
        if (c2 < c) { runA += SA[c2 * 512 + j]; runB += SB[c2 * 512 + j]; }
    }
    float bb2 = b2[j];
    int jt = ((j & 31) << 4) | (j >> 5);   // transposed offset within row
#pragma unroll 4
    for (int s = 0; s < 16; ++s) {
        int m = c * 16 + s;
        A[m * 512 + jt]   = runA;
        B2t[m * 512 + jt] = runB + bb2;
        int k = ksort[m];
        float w = W1[k], b = b1[k];
        float sgn = (w > 0.0f) ? 1.0f : ((w < 0.0f) ? -1.0f : 0.0f);
        float w2 = W2[k * 512 + j];
        runA = fmaf(sgn * w, w2, runA);
        runB = fmaf(sgn * b, w2, runB);
    }
    if (c == 31) {
        A[512 * 512 + jt]   = runA;
        B2t[512 * 512 + jt] = runB + bb2;
    }
}

// ---------------------------------------------------------------------------
// K3: per-edge message, 32 lanes/edge. NO atomics: lane o stores bf16 msg to
// msgbuf[eslot[e]*32 + o] (each CSR slot written exactly once).
// ---------------------------------------------------------------------------
__global__ void __launch_bounds__(256) k3_edges(
        const float* __restrict__ x, const float* __restrict__ ea,
        const int* __restrict__ ei, const int* __restrict__ me,
        const int* __restrict__ eslot,
        const float* __restrict__ A, const float* __restrict__ B2t,
        unsigned short* __restrict__ msgbuf) {
    int gid = blockIdx.x * blockDim.x + threadIdx.x;
    int lane = gid & 31;
    int e = gid >> 5;
    if (e >= N_EDGES) return;
    float a = ea[e];
    int s = ei[e];
    int m = me[e];
    int slot = eslot[e];
    const float4* Ar = (const float4*)(A   + m * 512 + lane * 16);
    const float4* Br = (const float4*)(B2t + m * 512 + lane * 16);
    float4 a0 = Ar[0], a1 = Ar[1], a2 = Ar[2], a3 = Ar[3];
    float4 b0 = Br[0], b1 = Br[1], b2 = Br[2], b3 = Br[3];
    float xv = (lane < 16) ? x[s * 16 + lane] : 0.0f;
    float xa = 0.0f, xb = 0.0f;
    float xi;
    xi = __shfl(xv,  0, 32); xa = fmaf(xi, a0.x, xa); xb = fmaf(xi, b0.x, xb);
    xi = __shfl(xv,  1, 32); xa = fmaf(xi, a0.y, xa); xb = fmaf(xi, b0.y, xb);
    xi = __shfl(xv,  2, 32); xa = fmaf(xi, a0.z, xa); xb = fmaf(xi, b0.z, xb);
    xi = __shfl(xv,  3, 32); xa = fmaf(xi, a0.w, xa); xb = fmaf(xi, b0.w, xb);
    xi = __shfl(xv,  4, 32); xa = fmaf(xi, a1.x, xa); xb = fmaf(xi, b1.x, xb);
    xi = __shfl(xv,  5, 32); xa = fmaf(xi, a1.y, xa); xb = fmaf(xi, b1.y, xb);
    xi = __shfl(xv,  6, 32); xa = fmaf(xi, a1.z, xa); xb = fmaf(xi, b1.z, xb);
    xi = __shfl(xv,  7, 32); xa = fmaf(xi, a1.w, xa); xb = fmaf(xi, b1.w, xb);
    xi = __shfl(xv,  8, 32); xa = fmaf(xi, a2.x, xa); xb = fmaf(xi, b2.x, xb);
    xi = __shfl(xv,  9, 32); xa = fmaf(xi, a2.y, xa); xb = fmaf(xi, b2.y, xb);
    xi = __shfl(xv, 10, 32); xa = fmaf(xi, a2.z, xa); xb = fmaf(xi, b2.z, xb);
    xi = __shfl(xv, 11, 32); xa = fmaf(xi, a2.w, xa); xb = fmaf(xi, b2.w, xb);
    xi = __shfl(xv, 12, 32); xa = fmaf(xi, a3.x, xa); xb = fmaf(xi, b3.x, xb);
    xi = __shfl(xv, 13, 32); xa = fmaf(xi, a3.y, xa); xb = fmaf(xi, b3.y, xb);
    xi = __shfl(xv, 14, 32); xa = fmaf(xi, a3.z, xa); xb = fmaf(xi, b3.z, xb);
    xi = __shfl(xv, 15, 32); xa = fmaf(xi, a3.w, xa); xb = fmaf(xi, b3.w, xb);
    float msg = fmaf(a, xa, xb);
    // f32 -> bf16 round-to-nearest-even
    unsigned int u = __float_as_uint(msg);
    u += 0x7FFFu + ((u >> 16) & 1u);
    msgbuf[slot * 32 + lane] = (unsigned short)(u >> 16);
}

// ---------------------------------------------------------------------------
// K4: per-node: stream-sum this node's contiguous msgbuf rows (bf16) ->
// aggr/cnt; h1 = relu(aggr + x@root + bias1); xw12[0..9] = h1@Wg;
// xw12[10] = rsqrt(indeg+1); [11] = 0.
// ---------------------------------------------------------------------------
__global__ void k4_nodes(const float* __restrict__ x, const int* __restrict__ offs,
                         const unsigned int* __restrict__ msgbuf,
                         const float* __restrict__ root, const float* __restrict__ bias1,
                         const float* __restrict__ Wg,
                         float* __restrict__ xw12) {
    __shared__ float sroot[512], sb1[32], swg[320];
    for (int i = threadIdx.x; i < 512; i += blockDim.x) sroot[i] = root[i];
    for (int i = threadIdx.x; i < 32; i += blockDim.x) sb1[i] = bias1[i];
    for (int i = threadIdx.x; i < 320; i += blockDim.x) swg[i] = Wg[i];
    __syncthreads();
    int n = blockIdx.x * blockDim.x + threadIdx.x;
    if (n >= N_NODES) return;
    int s0 = offs[n], s1 = offs[n + 1];
    float agg[32];
#pragma unroll
    for (int o = 0; o < 32; ++o) agg[o] = 0.0f;
    for (int sl = s0; sl < s1; ++sl) {
        const uint4* rp = (const uint4*)(msgbuf + sl * 16);  // 64B row = 32 bf16
#pragma unroll
        for (int q = 0; q < 4; ++q) {
            uint4 v = rp[q];
            agg[q * 8 + 0] += __uint_as_float(v.x << 16);
            agg[q * 8 + 1] += __uint_as_float(v.x & 0xFFFF0000u);
            agg[q * 8 + 2] += __uint_as_float(v.y << 16);
            agg[q * 8 + 3] += __uint_as_float(v.y & 0xFFFF0000u);
            agg[q * 8 + 4] += __uint_as_float(v.z << 16);
            agg[q * 8 + 5] += __uint_as_float(v.z & 0xFFFF0000u);
            agg[q * 8 + 6] += __uint_as_float(v.w << 16);
            agg[q * 8 + 7] += __uint_as_float(v.w & 0xFFFF0000u);
        }
    }
    float c = (float)(s1 - s0);
    float inv = 1.0f / fmaxf(c, 1.0f);
    const float4* xp = (const float4*)(x + n * 16);
    float xr[16];
#pragma unroll
    for (int q = 0; q < 4; ++q) {
        float4 v = xp[q];
        xr[q * 4 + 0] = v.x; xr[q * 4 + 1] = v.y;
        xr[q * 4 + 2] = v.z; xr[q * 4 + 3] = v.w;
    }
    float acc[10];
#pragma unroll
    for (int cc = 0; cc < 10; ++cc) acc[cc] = 0.0f;
#pragma unroll
    for (int o = 0; o < 32; ++o) {
        float h = agg[o] * inv + sb1[o];
#pragma unroll
        for (int i = 0; i < 16; ++i) h = fmaf(xr[i], sroot[i * 32 + o], h);
        h = fmaxf(h, 0.0f);
#pragma unroll
        for (int cc = 0; cc < 10; ++cc) acc[cc] = fmaf(h, swg[o * 10 + cc], acc[cc]);
    }
    float4* op = (float4*)(xw12 + n * 12);
    op[0] = make_float4(acc[0], acc[1], acc[2], acc[3]);
    op[1] = make_float4(acc[4], acc[5], acc[6], acc[7]);
    op[2] = make_float4(acc[8], acc[9], rsqrtf(c + 1.0f), 0.0f);
}

// ---------------------------------------------------------------------------
// K56: fused GCN gather + self-loop + bias + log_softmax -> d_out.
// ---------------------------------------------------------------------------
__global__ void k56_final(const int* __restrict__ offs, const int* __restrict__ ssrc,
                          const float* __restrict__ xw12,
                          const float* __restrict__ bg, float* __restrict__ out) {
    __shared__ float sbg[16];
    if (threadIdx.x < 10) sbg[threadIdx.x] = bg[threadIdx.x];
    __syncthreads();
    int n = blockIdx.x * blockDim.x + threadIdx.x;
    if (n >= N_NODES) return;
    const float4* base = (const float4*)xw12;
    float4 r0 = base[n * 3], r1 = base[n * 3 + 1], r2 = base[n * 3 + 2];
    float dn = r2.z;
    float d2 = dn * dn;
    float acc[10];
    acc[0] = fmaf(r0.x, d2, sbg[0]); acc[1] = fmaf(r0.y, d2, sbg[1]);
    acc[2] = fmaf(r0.z, d2, sbg[2]); acc[3] = fmaf(r0.w, d2, sbg[3]);
    acc[4] = fmaf(r1.x, d2, sbg[4]); acc[5] = fmaf(r1.y, d2, sbg[5]);
    acc[6] = fmaf(r1.z, d2, sbg[6]); acc[7] = fmaf(r1.w, d2, sbg[7]);
    acc[8] = fmaf(r2.x, d2, sbg[8]); acc[9] = fmaf(r2.y, d2, sbg[9]);
    int s0 = offs[n], s1 = offs[n + 1];
    for (int sl = s0; sl < s1; ++sl) {
        int s = ssrc[sl];
        float4 q0 = base[s * 3], q1 = base[s * 3 + 1], q2 = base[s * 3 + 2];
        float nf = q2.z * dn;
        acc[0] = fmaf(q0.x, nf, acc[0]); acc[1] = fmaf(q0.y, nf, acc[1]);
        acc[2] = fmaf(q0.z, nf, acc[2]); acc[3] = fmaf(q0.w, nf, acc[3]);
        acc[4] = fmaf(q1.x, nf, acc[4]); acc[5] = fmaf(q1.y, nf, acc[5]);
        acc[6] = fmaf(q1.z, nf, acc[6]); acc[7] = fmaf(q1.w, nf, acc[7]);
        acc[8] = fmaf(q2.x, nf, acc[8]); acc[9] = fmaf(q2.y, nf, acc[9]);
    }
    float mx = -1e30f;
#pragma unroll
    for (int c = 0; c < 10; ++c) mx = fmaxf(mx, acc[c]);
    float se = 0.0f;
#pragma unroll
    for (int c = 0; c < 10; ++c) se += expf(acc[c] - mx);
    float lse = logf(se) + mx;
#pragma unroll
    for (int c = 0; c < 10; ++c) out[n * 10 + c] = acc[c] - lse;
}

// ---------------------------------------------------------------------------
extern "C" void kernel_launch(void* const* d_in, const int* in_sizes, int n_in,
                              void* d_out, int out_size, void* d_ws, size_t ws_size,
                              hipStream_t stream) {
    const float* x     = (const float*)d_in[0];
    const float* ea    = (const float*)d_in[1];
    const float* W1    = (const float*)d_in[2];
    const float* b1    = (const float*)d_in[3];
    const float* W2    = (const float*)d_in[4];
    const float* b2    = (const float*)d_in[5];
    const float* root  = (const float*)d_in[6];
    const float* bias1 = (const float*)d_in[7];
    const float* Wg    = (const float*)d_in[8];
    const float* bg    = (const float*)d_in[9];
    const int*   ei    = (const int*)d_in[10];
    float* out = (float*)d_out;

    // workspace layout (4-byte units; float4/int4 segments 16B-aligned)
    float* A      = (float*)d_ws;                     // 513*512
    float* B2t    = A + 513 * 512;                    // 513*512
    float* tsort  = B2t + 513 * 512;                  // 512
    int*   ksort  = (int*)(tsort + 512);              // 512
    unsigned short* msgbuf = (unsigned short*)(ksort + 512); // E*32 bf16 = 2.4M units
    int*   deg    = (int*)((float*)msgbuf + 2400000); // N  <- zeroed
    int*   offs   = deg + N_NODES;                    // N+4
    int*   cur    = offs + N_NODES + 4;               // N
    int*   me     = cur + N_NODES;                    // E
    int*   eslot  = me + N_EDGES;                     // E
    int*   ssrc   = eslot + N_EDGES;                  // E
    float* xw12   = (float*)(ssrc + N_EDGES);         // N*12 (16B aligned)
    float* PbA    = xw12 + N_NODES * 12;              // 32*512
    float* PbB    = PbA + 32 * 512;
    float* SA     = PbB + 32 * 512;
    float* SB     = SA + 32 * 512;

    k0_zero<<<120, 256, 0, stream>>>(deg, N_NODES);
    k1_rank<<<1, 512, 0, stream>>>(W1, b1, tsort, ksort);
    kb1_prep<<<(N_EDGES + 255) / 256, 256, 0, stream>>>(ei, ea, tsort, deg, me);
    s_scan<<<1, 1024, 0, stream>>>(deg, offs, cur);
    kb3_fill<<<(N_EDGES + 255) / 256, 256, 0, stream>>>(ei, cur, ssrc, eslot);
    p1_chunks<<<64, 256, 0, stream>>>(W1, b1, W2, ksort, PbA, PbB, SA, SB);
    p3s_emit<<<64, 256, 0, stream>>>(W1, b1, b2, W2, ksort, PbA, PbB, SA, SB, A, B2t);
    k3_edges<<<(N_EDGES * 32 + 255) / 256, 256, 0, stream>>>(x, ea, ei, me, eslot,
                                                             A, B2t, msgbuf);
    k4_nodes<<<(N_NODES + 255) / 256, 256, 0, stream>>>(x, offs,
                                                        (const unsigned int*)msgbuf,
                                                        root, bias1, Wg, xw12);
    k56_final<<<(N_NODES + 255) / 256, 256, 0, stream>>>(offs, ssrc, xw12, bg, out);
}

// Round 8
// 163.628 us; speedup vs baseline: 1.4267x; 1.0703x over previous
//
#include <hip/hip_runtime.h>
#include <math.h>

#define N_NODES 30000
#define N_EDGES 150000
#define IN_F 16
#define H_F 32
#define C_F 10
// K = IN*H = 512 hidden units in the edge MLP; 513 piecewise-linear intervals.
// theta(a) = a*A_m + B2_m on interval m; tables TRANSPOSED as A_t[m][o][i]
// (o=0..31, i=0..15): lane o reads its 16 weights as 4 float4s. The emit
// kernels remap thread->output index so table WRITES stay coalesced and the
// W2 READS take the scatter (L1/L2-cached). k3 has no shfl/LDS: x_src is
// broadcast-loaded into registers by all 32 lanes of an edge group.

// ---------------------------------------------------------------------------
// K0: zero deg[N]
// ---------------------------------------------------------------------------
__global__ void k0_zero(int* __restrict__ p, int n) {
    int i = blockIdx.x * blockDim.x + threadIdx.x;
    int stride = gridDim.x * blockDim.x;
    for (; i < n; i += stride) p[i] = 0;
}

// ---------------------------------------------------------------------------
// K1: breakpoints t_k = -b1_k/W1_k, O(n^2) rank sort (no barriers in loop).
// ---------------------------------------------------------------------------
__global__ void k1_rank(const float* __restrict__ W1, const float* __restrict__ b1,
                        float* __restrict__ tsort, int* __restrict__ ksort) {
    __shared__ float st[512];
    int tid = threadIdx.x;
    float w = W1[tid], b = b1[tid];
    float t = (w != 0.0f) ? (-b / w) : 3.0e38f;
    st[tid] = t;
    __syncthreads();
    int rank = 0;
#pragma unroll 8
    for (int j = 0; j < 512; ++j) {
        float tj = st[j];
        rank += (tj < t || (tj == t && j < tid)) ? 1 : 0;
    }
    tsort[rank] = t;
    ksort[rank] = tid;
}

// ---------------------------------------------------------------------------
// KB1: per-edge prep: in-degree atomic (captures rank = old value) +
// interval m via binary search; rankm[e] = rank<<10 | m.
// ---------------------------------------------------------------------------
__global__ void kb1_prep(const int* __restrict__ ei, const float* __restrict__ ea,
                         const float* __restrict__ tsort,
                         int* __restrict__ deg, int* __restrict__ rankm) {
    __shared__ float ts[512];
    for (int i = threadIdx.x; i < 512; i += blockDim.x) ts[i] = tsort[i];
    __syncthreads();
    int e = blockIdx.x * blockDim.x + threadIdx.x;
    if (e >= N_EDGES) return;
    int rank = atomicAdd(&deg[ei[N_EDGES + e]], 1);
    float a = ea[e];
    int lo = 0, hi = 512;
    while (lo < hi) {
        int mid = (lo + hi) >> 1;
        if (ts[mid] < a) lo = mid + 1; else hi = mid;
    }
    rankm[e] = (rank << 10) | lo;
}

// ---------------------------------------------------------------------------
// S_SCAN: single block, 1024 threads: exclusive scan of deg -> offs.
// ---------------------------------------------------------------------------
__global__ void s_scan(const int* __restrict__ deg, int* __restrict__ offs) {
    __shared__ int part[1024];
    int t = threadIdx.x;
    int base = t * 30;
    int loc[30];
    int s = 0;
#pragma unroll
    for (int i = 0; i < 30; ++i) {
        int idx = base + i;
        int v = (idx < N_NODES) ? deg[idx] : 0;
        loc[i] = v;
        s += v;
    }
    part[t] = s;
    __syncthreads();
    for (int off = 1; off < 1024; off <<= 1) {
        int v = part[t];
        int add = (t >= off) ? part[t - off] : 0;
        __syncthreads();
        part[t] = v + add;
        __syncthreads();
    }
    int run = (t > 0) ? part[t - 1] : 0;
#pragma unroll
    for (int i = 0; i < 30; ++i) {
        int idx = base + i;
        if (idx < N_NODES) offs[idx] = run;
        run += loc[i];
    }
    if (t == 1023) offs[N_NODES] = run;
}

// ---------------------------------------------------------------------------
// KB3: dst-CSR source-list fill, ATOMIC-FREE: slot = offs[d] + rank.
// ---------------------------------------------------------------------------
__global__ void kb3_fill(const int* __restrict__ ei, const int* __restrict__ rankm,
                         const int* __restrict__ offs, int* __restrict__ ssrc) {
    int e = blockIdx.x * blockDim.x + threadIdx.x;
    if (e >= N_EDGES) return;
    int s = ei[e], d = ei[N_EDGES + e];
    int slot = offs[d] + (rankm[e] >> 10);
    ssrc[slot] = s;
}

// ---------------------------------------------------------------------------
// P1: per-chunk partial sums over 32 chunks of 16 ranks.
// Thread owns storage index jt (coalesced PbA writes); W2 column is
// jsrc = (jt&15)*32 + (jt>>4) (scattered reads, cached).
// ---------------------------------------------------------------------------
__global__ void p1_chunks(const float* __restrict__ W1, const float* __restrict__ b1,
                          const float* __restrict__ W2, const int* __restrict__ ksort,
                          float* __restrict__ PbA, float* __restrict__ PbB,
                          float* __restrict__ SA, float* __restrict__ SB) {
    int c = blockIdx.x & 31;
    int jc = blockIdx.x >> 5;
    int jt = jc * 256 + threadIdx.x;
    int jsrc = ((jt & 15) << 5) | (jt >> 4);
    float ba = 0.0f, bb = 0.0f, sa = 0.0f, sb = 0.0f;
#pragma unroll 4
    for (int s = 0; s < 16; ++s) {
        int k = c * 16 + s;
        float w = W1[k], b = b1[k];
        bool act = (w < 0.0f) || (w == 0.0f && b > 0.0f);
        if (act) {
            float w2 = W2[k * 512 + jsrc];
            ba = fmaf(w, w2, ba);
            bb = fmaf(b, w2, bb);
        }
        int kr = ksort[c * 16 + s];
        float wr = W1[kr], br = b1[kr];
        float sgn = (wr > 0.0f) ? 1.0f : ((wr < 0.0f) ? -1.0f : 0.0f);
        float w2r = W2[kr * 512 + jsrc];
        sa = fmaf(sgn * wr, w2r, sa);
        sb = fmaf(sgn * br, w2r, sb);
    }
    PbA[c * 512 + jt] = ba; PbB[c * 512 + jt] = bb;
    SA[c * 512 + jt] = sa;  SB[c * 512 + jt] = sb;
}

// ---------------------------------------------------------------------------
// P3S: fused scan + emit. All accesses to PbA/SA/A/B2t use jt (coalesced);
// W2/b2 use jsrc. A[m*512+jt] is exactly A_t[m][o][i] with jt = o*16+i.
// ---------------------------------------------------------------------------
__global__ void p3s_emit(const float* __restrict__ W1, const float* __restrict__ b1,
                         const float* __restrict__ b2, const float* __restrict__ W2,
                         const int* __restrict__ ksort,
                         const float* __restrict__ PbA, const float* __restrict__ PbB,
                         const float* __restrict__ SA, const float* __restrict__ SB,
                         float* __restrict__ A, float* __restrict__ B2t) {
    int c = blockIdx.x & 31;
    int jc = blockIdx.x >> 5;
    int jt = jc * 256 + threadIdx.x;
    int jsrc = ((jt & 15) << 5) | (jt >> 4);
    float runA = 0.0f, runB = 0.0f;
#pragma unroll
    for (int c2 = 0; c2 < 32; ++c2) {
        runA += PbA[c2 * 512 + jt];
        runB += PbB[c2 * 512 + jt];
        if (c2 < c) { runA += SA[c2 * 512 + jt]; runB += SB[c2 * 512 + jt]; }
    }
    float bb2 = b2[jsrc];
#pragma unroll 4
    for (int s = 0; s < 16; ++s) {
        int m = c * 16 + s;
        A[m * 512 + jt]   = runA;
        B2t[m * 512 + jt] = runB + bb2;
        int k = ksort[m];
        float w = W1[k], b = b1[k];
        float sgn = (w > 0.0f) ? 1.0f : ((w < 0.0f) ? -1.0f : 0.0f);
        float w2 = W2[k * 512 + jsrc];
        runA = fmaf(sgn * w, w2, runA);
        runB = fmaf(sgn * b, w2, runB);
    }
    if (c == 31) {
        A[512 * 512 + jt]   = runA;
        B2t[512 * 512 + jt] = runB + bb2;
    }
}

// ---------------------------------------------------------------------------
// K3: per-edge message, 32 lanes/edge, NO shfl/LDS. All lanes broadcast-load
// x_src (4 float4s); lane o reads its transposed table rows (4+4 float4s);
// slot computed from offs[dst] + rank; bf16 store (exactly-once per slot).
// ---------------------------------------------------------------------------
__global__ void __launch_bounds__(256) k3_edges(
        const float* __restrict__ x, const float* __restrict__ ea,
        const int* __restrict__ ei, const int* __restrict__ rankm,
        const int* __restrict__ offs,
        const float* __restrict__ A, const float* __restrict__ B2t,
        unsigned short* __restrict__ msgbuf) {
    int gid = blockIdx.x * blockDim.x + threadIdx.x;
    int lane = gid & 31;
    int e = gid >> 5;
    if (e >= N_EDGES) return;
    float a = ea[e];
    int s = ei[e], d = ei[N_EDGES + e];
    int rm = rankm[e];
    int m = rm & 1023;
    int slot = offs[d] + (rm >> 10);
    const float4* Ar = (const float4*)(A   + m * 512 + lane * 16);
    const float4* Br = (const float4*)(B2t + m * 512 + lane * 16);
    float4 a0 = Ar[0], a1 = Ar[1], a2 = Ar[2], a3 = Ar[3];
    float4 b0 = Br[0], b1 = Br[1], b2 = Br[2], b3 = Br[3];
    const float4* xp = (const float4*)(x + s * 16);
    float4 x0 = xp[0], x1 = xp[1], x2 = xp[2], x3 = xp[3];
    float xa = 0.0f, xb = 0.0f;
    xa = fmaf(x0.x, a0.x, xa); xb = fmaf(x0.x, b0.x, xb);
    xa = fmaf(x0.y, a0.y, xa); xb = fmaf(x0.y, b0.y, xb);
    xa = fmaf(x0.z, a0.z, xa); xb = fmaf(x0.z, b0.z, xb);
    xa = fmaf(x0.w, a0.w, xa); xb = fmaf(x0.w, b0.w, xb);
    xa = fmaf(x1.x, a1.x, xa); xb = fmaf(x1.x, b1.x, xb);
    xa = fmaf(x1.y, a1.y, xa); xb = fmaf(x1.y, b1.y, xb);
    xa = fmaf(x1.z, a1.z, xa); xb = fmaf(x1.z, b1.z, xb);
    xa = fmaf(x1.w, a1.w, xa); xb = fmaf(x1.w, b1.w, xb);
    xa = fmaf(x2.x, a2.x, xa); xb = fmaf(x2.x, b2.x, xb);
    xa = fmaf(x2.y, a2.y, xa); xb = fmaf(x2.y, b2.y, xb);
    xa = fmaf(x2.z, a2.z, xa); xb = fmaf(x2.z, b2.z, xb);
    xa = fmaf(x2.w, a2.w, xa); xb = fmaf(x2.w, b2.w, xb);
    xa = fmaf(x3.x, a3.x, xa); xb = fmaf(x3.x, b3.x, xb);
    xa = fmaf(x3.y, a3.y, xa); xb = fmaf(x3.y, b3.y, xb);
    xa = fmaf(x3.z, a3.z, xa); xb = fmaf(x3.z, b3.z, xb);
    xa = fmaf(x3.w, a3.w, xa); xb = fmaf(x3.w, b3.w, xb);
    float msg = fmaf(a, xa, xb);
    // f32 -> bf16 round-to-nearest-even
    unsigned int u = __float_as_uint(msg);
    u += 0x7FFFu + ((u >> 16) & 1u);
    msgbuf[slot * 32 + lane] = (unsigned short)(u >> 16);
}

// ---------------------------------------------------------------------------
// K4: per-node: stream-sum contiguous msgbuf rows (bf16) -> aggr; h1 =
// relu(aggr/cnt + x@root + bias1); xw12[0..9] = h1@Wg; [10] = rsqrt(deg+1).
// ---------------------------------------------------------------------------
__global__ void k4_nodes(const float* __restrict__ x, const int* __restrict__ offs,
                         const unsigned int* __restrict__ msgbuf,
                         const float* __restrict__ root, const float* __restrict__ bias1,
                         const float* __restrict__ Wg,
                         float* __restrict__ xw12) {
    __shared__ float sroot[512], sb1[32], swg[320];
    for (int i = threadIdx.x; i < 512; i += blockDim.x) sroot[i] = root[i];
    for (int i = threadIdx.x; i < 32; i += blockDim.x) sb1[i] = bias1[i];
    for (int i = threadIdx.x; i < 320; i += blockDim.x) swg[i] = Wg[i];
    __syncthreads();
    int n = blockIdx.x * blockDim.x + threadIdx.x;
    if (n >= N_NODES) return;
    int s0 = offs[n], s1 = offs[n + 1];
    float agg[32];
#pragma unroll
    for (int o = 0; o < 32; ++o) agg[o] = 0.0f;
    for (int sl = s0; sl < s1; ++sl) {
        const uint4* rp = (const uint4*)(msgbuf + sl * 16);  // 64B row = 32 bf16
#pragma unroll
        for (int q = 0; q < 4; ++q) {
            uint4 v = rp[q];
            agg[q * 8 + 0] += __uint_as_float(v.x << 16);
            agg[q * 8 + 1] += __uint_as_float(v.x & 0xFFFF0000u);
            agg[q * 8 + 2] += __uint_as_float(v.y << 16);
            agg[q * 8 + 3] += __uint_as_float(v.y & 0xFFFF0000u);
            agg[q * 8 + 4] += __uint_as_float(v.z << 16);
            agg[q * 8 + 5] += __uint_as_float(v.z & 0xFFFF0000u);
            agg[q * 8 + 6] += __uint_as_float(v.w << 16);
            agg[q * 8 + 7] += __uint_as_float(v.w & 0xFFFF0000u);
        }
    }
    float c = (float)(s1 - s0);
    float inv = 1.0f / fmaxf(c, 1.0f);
    const float4* xp = (const float4*)(x + n * 16);
    float xr[16];
#pragma unroll
    for (int q = 0; q < 4; ++q) {
        float4 v = xp[q];
        xr[q * 4 + 0] = v.x; xr[q * 4 + 1] = v.y;
        xr[q * 4 + 2] = v.z; xr[q * 4 + 3] = v.w;
    }
    float acc[10];
#pragma unroll
    for (int cc = 0; cc < 10; ++cc) acc[cc] = 0.0f;
#pragma unroll
    for (int o = 0; o < 32; ++o) {
        float h = agg[o] * inv + sb1[o];
#pragma unroll
        for (int i = 0; i < 16; ++i) h = fmaf(xr[i], sroot[i * 32 + o], h);
        h = fmaxf(h, 0.0f);
#pragma unroll
        for (int cc = 0; cc < 10; ++cc) acc[cc] = fmaf(h, swg[o * 10 + cc], acc[cc]);
    }
    float4* op = (float4*)(xw12 + n * 12);
    op[0] = make_float4(acc[0], acc[1], acc[2], acc[3]);
    op[1] = make_float4(acc[4], acc[5], acc[6], acc[7]);
    op[2] = make_float4(acc[8], acc[9], rsqrtf(c + 1.0f), 0.0f);
}

// ---------------------------------------------------------------------------
// K56: fused GCN gather + self-loop + bias + log_softmax -> d_out.
// ---------------------------------------------------------------------------
__global__ void k56_final(const int* __restrict__ offs, const int* __restrict__ ssrc,
                          const float* __restrict__ xw12,
                          const float* __restrict__ bg, float* __restrict__ out) {
    __shared__ float sbg[16];
    if (threadIdx.x < 10) sbg[threadIdx.x] = bg[threadIdx.x];
    __syncthreads();
    int n = blockIdx.x * blockDim.x + threadIdx.x;
    if (n >= N_NODES) return;
    const float4* base = (const float4*)xw12;
    float4 r0 = base[n * 3], r1 = base[n * 3 + 1], r2 = base[n * 3 + 2];
    float dn = r2.z;
    float d2 = dn * dn;
    float acc[10];
    acc[0] = fmaf(r0.x, d2, sbg[0]); acc[1] = fmaf(r0.y, d2, sbg[1]);
    acc[2] = fmaf(r0.z, d2, sbg[2]); acc[3] = fmaf(r0.w, d2, sbg[3]);
    acc[4] = fmaf(r1.x, d2, sbg[4]); acc[5] = fmaf(r1.y, d2, sbg[5]);
    acc[6] = fmaf(r1.z, d2, sbg[6]); acc[7] = fmaf(r1.w, d2, sbg[7]);
    acc[8] = fmaf(r2.x, d2, sbg[8]); acc[9] = fmaf(r2.y, d2, sbg[9]);
    int s0 = offs[n], s1 = offs[n + 1];
    for (int sl = s0; sl < s1; ++sl) {
        int s = ssrc[sl];
        float4 q0 = base[s * 3], q1 = base[s * 3 + 1], q2 = base[s * 3 + 2];
        float nf = q2.z * dn;
        acc[0] = fmaf(q0.x, nf, acc[0]); acc[1] = fmaf(q0.y, nf, acc[1]);
        acc[2] = fmaf(q0.z, nf, acc[2]); acc[3] = fmaf(q0.w, nf, acc[3]);
        acc[4] = fmaf(q1.x, nf, acc[4]); acc[5] = fmaf(q1.y, nf, acc[5]);
        acc[6] = fmaf(q1.z, nf, acc[6]); acc[7] = fmaf(q1.w, nf, acc[7]);
        acc[8] = fmaf(q2.x, nf, acc[8]); acc[9] = fmaf(q2.y, nf, acc[9]);
    }
    float mx = -1e30f;
#pragma unroll
    for (int c = 0; c < 10; ++c) mx = fmaxf(mx, acc[c]);
    float se = 0.0f;
#pragma unroll
    for (int c = 0; c < 10; ++c) se += expf(acc[c] - mx);
    float lse = logf(se) + mx;
#pragma unroll
    for (int c = 0; c < 10; ++c) out[n * 10 + c] = acc[c] - lse;
}

// ---------------------------------------------------------------------------
extern "C" void kernel_launch(void* const* d_in, const int* in_sizes, int n_in,
                              void* d_out, int out_size, void* d_ws, size_t ws_size,
                              hipStream_t stream) {
    const float* x     = (const float*)d_in[0];
    const float* ea    = (const float*)d_in[1];
    const float* W1    = (const float*)d_in[2];
    const float* b1    = (const float*)d_in[3];
    const float* W2    = (const float*)d_in[4];
    const float* b2    = (const float*)d_in[5];
    const float* root  = (const float*)d_in[6];
    const float* bias1 = (const float*)d_in[7];
    const float* Wg    = (const float*)d_in[8];
    const float* bg    = (const float*)d_in[9];
    const int*   ei    = (const int*)d_in[10];
    float* out = (float*)d_out;

    // workspace layout (4-byte units; 16B-aligned segments)
    float* A      = (float*)d_ws;                     // 513*512
    float* B2t    = A + 513 * 512;                    // 513*512
    float* tsort  = B2t + 513 * 512;                  // 512
    int*   ksort  = (int*)(tsort + 512);              // 512
    unsigned short* msgbuf = (unsigned short*)(ksort + 512); // E*32 bf16 (2.4M units)
    int*   deg    = (int*)((float*)msgbuf + 2400000); // N  <- zeroed
    int*   offs   = deg + N_NODES;                    // N+4
    int*   rankm  = offs + N_NODES + 4;               // E
    int*   ssrc   = rankm + N_EDGES;                  // E
    float* xw12   = (float*)(ssrc + N_EDGES);         // N*12 (16B aligned)
    float* PbA    = xw12 + N_NODES * 12;              // 32*512
    float* PbB    = PbA + 32 * 512;
    float* SA     = PbB + 32 * 512;
    float* SB     = SA + 32 * 512;

    k0_zero<<<120, 256, 0, stream>>>(deg, N_NODES);
    k1_rank<<<1, 512, 0, stream>>>(W1, b1, tsort, ksort);
    kb1_prep<<<(N_EDGES + 255) / 256, 256, 0, stream>>>(ei, ea, tsort, deg, rankm);
    s_scan<<<1, 1024, 0, stream>>>(deg, offs);
    kb3_fill<<<(N_EDGES + 255) / 256, 256, 0, stream>>>(ei, rankm, offs, ssrc);
    p1_chunks<<<64, 256, 0, stream>>>(W1, b1, W2, ksort, PbA, PbB, SA, SB);
    p3s_emit<<<64, 256, 0, stream>>>(W1, b1, b2, W2, ksort, PbA, PbB, SA, SB, A, B2t);
    k3_edges<<<(N_EDGES * 32 + 255) / 256, 256, 0, stream>>>(x, ea, ei, rankm, offs,
                                                             A, B2t, msgbuf);
    k4_nodes<<<(N_NODES + 255) / 256, 256, 0, stream>>>(x, offs,
                                                        (const unsigned int*)msgbuf,
                                                        root, bias1, Wg, xw12);
    k56_final<<<(N_NODES + 255) / 256, 256, 0, stream>>>(offs, ssrc, xw12, bg, out);
}

// Round 9
// 134.875 us; speedup vs baseline: 1.7309x; 1.2132x over previous
//
#include <hip/hip_runtime.h>
#include <math.h>

#define N_NODES 30000
#define N_EDGES 150000
#define IN_F 16
#define H_F 32
#define C_F 10
// K = IN*H = 512 hidden units in the edge MLP; 513 piecewise-linear intervals.
// theta(a) = a*A_m + B2_m on interval m. Tables packed: one uint32 per entry,
// hi16 = bf16(A), lo16 = bf16(B2), transposed layout T[m][o*16+i] so lane o
// reads its 32 weights as 4 uint4s (64B own line). k3 is L2-BW-bound on table
// reads; packing halves bytes/edge (4KB -> 2KB).

__device__ __forceinline__ unsigned bf16_rne(float f) {
    unsigned u = __float_as_uint(f);
    u += 0x7FFFu + ((u >> 16) & 1u);
    return u >> 16;
}

// ---------------------------------------------------------------------------
// K1: breakpoints t_k = -b1_k/W1_k, O(n^2) rank sort (no barriers in loop).
// ---------------------------------------------------------------------------
__global__ void k1_rank(const float* __restrict__ W1, const float* __restrict__ b1,
                        float* __restrict__ tsort, int* __restrict__ ksort) {
    __shared__ float st[512];
    int tid = threadIdx.x;
    float w = W1[tid], b = b1[tid];
    float t = (w != 0.0f) ? (-b / w) : 3.0e38f;
    st[tid] = t;
    __syncthreads();
    int rank = 0;
#pragma unroll 8
    for (int j = 0; j < 512; ++j) {
        float tj = st[j];
        rank += (tj < t || (tj == t && j < tid)) ? 1 : 0;
    }
    tsort[rank] = t;
    ksort[rank] = tid;
}

// ---------------------------------------------------------------------------
// KB1: per-edge prep: in-degree atomic (old value = rank within dst) +
// interval m via binary search; rankm[e] = rank<<10 | m.
// ---------------------------------------------------------------------------
__global__ void kb1_prep(const int* __restrict__ ei, const float* __restrict__ ea,
                         const float* __restrict__ tsort,
                         int* __restrict__ deg, int* __restrict__ rankm) {
    __shared__ float ts[512];
    for (int i = threadIdx.x; i < 512; i += blockDim.x) ts[i] = tsort[i];
    __syncthreads();
    int e = blockIdx.x * blockDim.x + threadIdx.x;
    if (e >= N_EDGES) return;
    int rank = atomicAdd(&deg[ei[N_EDGES + e]], 1);
    float a = ea[e];
    int lo = 0, hi = 512;
    while (lo < hi) {
        int mid = (lo + hi) >> 1;
        if (ts[mid] < a) lo = mid + 1; else hi = mid;
    }
    rankm[e] = (rank << 10) | lo;
}

// ---------------------------------------------------------------------------
// S_SCAN: single block, 1024 threads: exclusive scan of deg -> offs.
// ---------------------------------------------------------------------------
__global__ void s_scan(const int* __restrict__ deg, int* __restrict__ offs) {
    __shared__ int part[1024];
    int t = threadIdx.x;
    int base = t * 30;
    int loc[30];
    int s = 0;
#pragma unroll
    for (int i = 0; i < 30; ++i) {
        int idx = base + i;
        int v = (idx < N_NODES) ? deg[idx] : 0;
        loc[i] = v;
        s += v;
    }
    part[t] = s;
    __syncthreads();
    for (int off = 1; off < 1024; off <<= 1) {
        int v = part[t];
        int add = (t >= off) ? part[t - off] : 0;
        __syncthreads();
        part[t] = v + add;
        __syncthreads();
    }
    int run = (t > 0) ? part[t - 1] : 0;
#pragma unroll
    for (int i = 0; i < 30; ++i) {
        int idx = base + i;
        if (idx < N_NODES) offs[idx] = run;
        run += loc[i];
    }
    if (t == 1023) offs[N_NODES] = run;
}

// ---------------------------------------------------------------------------
// P1: per-chunk partial sums over 32 chunks of 16 ranks. Thread owns storage
// index jt (coalesced writes); W2 column jsrc = (jt&15)*32 + (jt>>4).
// ---------------------------------------------------------------------------
__global__ void p1_chunks(const float* __restrict__ W1, const float* __restrict__ b1,
                          const float* __restrict__ W2, const int* __restrict__ ksort,
                          float* __restrict__ PbA, float* __restrict__ PbB,
                          float* __restrict__ SA, float* __restrict__ SB) {
    int c = blockIdx.x & 31;
    int jc = blockIdx.x >> 5;
    int jt = jc * 256 + threadIdx.x;
    int jsrc = ((jt & 15) << 5) | (jt >> 4);
    float ba = 0.0f, bb = 0.0f, sa = 0.0f, sb = 0.0f;
#pragma unroll 4
    for (int s = 0; s < 16; ++s) {
        int k = c * 16 + s;
        float w = W1[k], b = b1[k];
        bool act = (w < 0.0f) || (w == 0.0f && b > 0.0f);
        if (act) {
            float w2 = W2[k * 512 + jsrc];
            ba = fmaf(w, w2, ba);
            bb = fmaf(b, w2, bb);
        }
        int kr = ksort[c * 16 + s];
        float wr = W1[kr], br = b1[kr];
        float sgn = (wr > 0.0f) ? 1.0f : ((wr < 0.0f) ? -1.0f : 0.0f);
        float w2r = W2[kr * 512 + jsrc];
        sa = fmaf(sgn * wr, w2r, sa);
        sb = fmaf(sgn * br, w2r, sb);
    }
    PbA[c * 512 + jt] = ba; PbB[c * 512 + jt] = bb;
    SA[c * 512 + jt] = sa;  SB[c * 512 + jt] = sb;
}

// ---------------------------------------------------------------------------
// P3S: fused scan + emit of PACKED table T[m*512+jt] = bf16(A)<<16|bf16(B2).
// Running sums stay f32; only the stored entries are bf16.
// ---------------------------------------------------------------------------
__global__ void p3s_emit(const float* __restrict__ W1, const float* __restrict__ b1,
                         const float* __restrict__ b2, const float* __restrict__ W2,
                         const int* __restrict__ ksort,
                         const float* __restrict__ PbA, const float* __restrict__ PbB,
                         const float* __restrict__ SA, const float* __restrict__ SB,
                         unsigned int* __restrict__ T) {
    int c = blockIdx.x & 31;
    int jc = blockIdx.x >> 5;
    int jt = jc * 256 + threadIdx.x;
    int jsrc = ((jt & 15) << 5) | (jt >> 4);
    float runA = 0.0f, runB = 0.0f;
#pragma unroll
    for (int c2 = 0; c2 < 32; ++c2) {
        runA += PbA[c2 * 512 + jt];
        runB += PbB[c2 * 512 + jt];
        if (c2 < c) { runA += SA[c2 * 512 + jt]; runB += SB[c2 * 512 + jt]; }
    }
    float bb2 = b2[jsrc];
#pragma unroll 4
    for (int s = 0; s < 16; ++s) {
        int m = c * 16 + s;
        T[m * 512 + jt] = (bf16_rne(runA) << 16) | bf16_rne(runB + bb2);
        int k = ksort[m];
        float w = W1[k], b = b1[k];
        float sgn = (w > 0.0f) ? 1.0f : ((w < 0.0f) ? -1.0f : 0.0f);
        float w2 = W2[k * 512 + jsrc];
        runA = fmaf(sgn * w, w2, runA);
        runB = fmaf(sgn * b, w2, runB);
    }
    if (c == 31) {
        T[512 * 512 + jt] = (bf16_rne(runA) << 16) | bf16_rne(runB + bb2);
    }
}

// ---------------------------------------------------------------------------
// K3: per-edge message, 32 lanes/edge. Lane o: 4 uint4 loads of packed
// (A,B2) weights; x broadcast via shfl from lanes 0..15; slot computed from
// offs[dst]+rank; bf16 store; lane 0 also fills ssrc[slot] (fused CSR fill).
// ---------------------------------------------------------------------------
__global__ void __launch_bounds__(256) k3_edges(
        const float* __restrict__ x, const float* __restrict__ ea,
        const int* __restrict__ ei, const int* __restrict__ rankm,
        const int* __restrict__ offs, const unsigned int* __restrict__ T,
        unsigned short* __restrict__ msgbuf, int* __restrict__ ssrc) {
    int gid = blockIdx.x * blockDim.x + threadIdx.x;
    int lane = gid & 31;
    int e = gid >> 5;
    if (e >= N_EDGES) return;
    float a = ea[e];
    int s = ei[e], d = ei[N_EDGES + e];
    int rm = rankm[e];
    int m = rm & 1023;
    int slot = offs[d] + (rm >> 10);
    const uint4* Tr = (const uint4*)(T + m * 512 + lane * 16);
    uint4 t0 = Tr[0], t1 = Tr[1], t2 = Tr[2], t3 = Tr[3];
    float xv = (lane < 16) ? x[s * 16 + lane] : 0.0f;
    float xa = 0.0f, xb = 0.0f;
    float xi;
#define STEP(w, i)                                                         \
    xi = __shfl(xv, i, 32);                                                \
    xa = fmaf(xi, __uint_as_float((w) & 0xFFFF0000u), xa);                 \
    xb = fmaf(xi, __uint_as_float((w) << 16), xb);
    STEP(t0.x, 0)  STEP(t0.y, 1)  STEP(t0.z, 2)  STEP(t0.w, 3)
    STEP(t1.x, 4)  STEP(t1.y, 5)  STEP(t1.z, 6)  STEP(t1.w, 7)
    STEP(t2.x, 8)  STEP(t2.y, 9)  STEP(t2.z, 10) STEP(t2.w, 11)
    STEP(t3.x, 12) STEP(t3.y, 13) STEP(t3.z, 14) STEP(t3.w, 15)
#undef STEP
    float msg = fmaf(a, xa, xb);
    unsigned int u = __float_as_uint(msg);
    u += 0x7FFFu + ((u >> 16) & 1u);
    msgbuf[slot * 32 + lane] = (unsigned short)(u >> 16);
    if (lane == 0) ssrc[slot] = s;
}

// ---------------------------------------------------------------------------
// K4: per-node: stream-sum contiguous msgbuf rows (bf16) -> aggr; h1 =
// relu(aggr/cnt + x@root + bias1); xw12[0..9] = h1@Wg; [10] = rsqrt(deg+1).
// ---------------------------------------------------------------------------
__global__ void k4_nodes(const float* __restrict__ x, const int* __restrict__ offs,
                         const unsigned int* __restrict__ msgbuf,
                         const float* __restrict__ root, const float* __restrict__ bias1,
                         const float* __restrict__ Wg,
                         float* __restrict__ xw12) {
    __shared__ float sroot[512], sb1[32], swg[320];
    for (int i = threadIdx.x; i < 512; i += blockDim.x) sroot[i] = root[i];
    for (int i = threadIdx.x; i < 32; i += blockDim.x) sb1[i] = bias1[i];
    for (int i = threadIdx.x; i < 320; i += blockDim.x) swg[i] = Wg[i];
    __syncthreads();
    int n = blockIdx.x * blockDim.x + threadIdx.x;
    if (n >= N_NODES) return;
    int s0 = offs[n], s1 = offs[n + 1];
    float agg[32];
#pragma unroll
    for (int o = 0; o < 32; ++o) agg[o] = 0.0f;
    for (int sl = s0; sl < s1; ++sl) {
        const uint4* rp = (const uint4*)(msgbuf + sl * 16);  // 64B row = 32 bf16
#pragma unroll
        for (int q = 0; q < 4; ++q) {
            uint4 v = rp[q];
            agg[q * 8 + 0] += __uint_as_float(v.x << 16);
            agg[q * 8 + 1] += __uint_as_float(v.x & 0xFFFF0000u);
            agg[q * 8 + 2] += __uint_as_float(v.y << 16);
            agg[q * 8 + 3] += __uint_as_float(v.y & 0xFFFF0000u);
            agg[q * 8 + 4] += __uint_as_float(v.z << 16);
            agg[q * 8 + 5] += __uint_as_float(v.z & 0xFFFF0000u);
            agg[q * 8 + 6] += __uint_as_float(v.w << 16);
            agg[q * 8 + 7] += __uint_as_float(v.w & 0xFFFF0000u);
        }
    }
    float c = (float)(s1 - s0);
    float inv = 1.0f / fmaxf(c, 1.0f);
    const float4* xp = (const float4*)(x + n * 16);
    float xr[16];
#pragma unroll
    for (int q = 0; q < 4; ++q) {
        float4 v = xp[q];
        xr[q * 4 + 0] = v.x; xr[q * 4 + 1] = v.y;
        xr[q * 4 + 2] = v.z; xr[q * 4 + 3] = v.w;
    }
    float acc[10];
#pragma unroll
    for (int cc = 0; cc < 10; ++cc) acc[cc] = 0.0f;
#pragma unroll
    for (int o = 0; o < 32; ++o) {
        float h = agg[o] * inv + sb1[o];
#pragma unroll
        for (int i = 0; i < 16; ++i) h = fmaf(xr[i], sroot[i * 32 + o], h);
        h = fmaxf(h, 0.0f);
#pragma unroll
        for (int cc = 0; cc < 10; ++cc) acc[cc] = fmaf(h, swg[o * 10 + cc], acc[cc]);
    }
    float4* op = (float4*)(xw12 + n * 12);
    op[0] = make_float4(acc[0], acc[1], acc[2], acc[3]);
    op[1] = make_float4(acc[4], acc[5], acc[6], acc[7]);
    op[2] = make_float4(acc[8], acc[9], rsqrtf(c + 1.0f), 0.0f);
}

// ---------------------------------------------------------------------------
// K56: fused GCN gather + self-loop + bias + log_softmax -> d_out.
// ---------------------------------------------------------------------------
__global__ void k56_final(const int* __restrict__ offs, const int* __restrict__ ssrc,
                          const float* __restrict__ xw12,
                          const float* __restrict__ bg, float* __restrict__ out) {
    __shared__ float sbg[16];
    if (threadIdx.x < 10) sbg[threadIdx.x] = bg[threadIdx.x];
    __syncthreads();
    int n = blockIdx.x * blockDim.x + threadIdx.x;
    if (n >= N_NODES) return;
    const float4* base = (const float4*)xw12;
    float4 r0 = base[n * 3], r1 = base[n * 3 + 1], r2 = base[n * 3 + 2];
    float dn = r2.z;
    float d2 = dn * dn;
    float acc[10];
    acc[0] = fmaf(r0.x, d2, sbg[0]); acc[1] = fmaf(r0.y, d2, sbg[1]);
    acc[2] = fmaf(r0.z, d2, sbg[2]); acc[3] = fmaf(r0.w, d2, sbg[3]);
    acc[4] = fmaf(r1.x, d2, sbg[4]); acc[5] = fmaf(r1.y, d2, sbg[5]);
    acc[6] = fmaf(r1.z, d2, sbg[6]); acc[7] = fmaf(r1.w, d2, sbg[7]);
    acc[8] = fmaf(r2.x, d2, sbg[8]); acc[9] = fmaf(r2.y, d2, sbg[9]);
    int s0 = offs[n], s1 = offs[n + 1];
    for (int sl = s0; sl < s1; ++sl) {
        int s = ssrc[sl];
        float4 q0 = base[s * 3], q1 = base[s * 3 + 1], q2 = base[s * 3 + 2];
        float nf = q2.z * dn;
        acc[0] = fmaf(q0.x, nf, acc[0]); acc[1] = fmaf(q0.y, nf, acc[1]);
        acc[2] = fmaf(q0.z, nf, acc[2]); acc[3] = fmaf(q0.w, nf, acc[3]);
        acc[4] = fmaf(q1.x, nf, acc[4]); acc[5] = fmaf(q1.y, nf, acc[5]);
        acc[6] = fmaf(q1.z, nf, acc[6]); acc[7] = fmaf(q1.w, nf, acc[7]);
        acc[8] = fmaf(q2.x, nf, acc[8]); acc[9] = fmaf(q2.y, nf, acc[9]);
    }
    float mx = -1e30f;
#pragma unroll
    for (int c = 0; c < 10; ++c) mx = fmaxf(mx, acc[c]);
    float se = 0.0f;
#pragma unroll
    for (int c = 0; c < 10; ++c) se += expf(acc[c] - mx);
    float lse = logf(se) + mx;
#pragma unroll
    for (int c = 0; c < 10; ++c) out[n * 10 + c] = acc[c] - lse;
}

// ---------------------------------------------------------------------------
extern "C" void kernel_launch(void* const* d_in, const int* in_sizes, int n_in,
                              void* d_out, int out_size, void* d_ws, size_t ws_size,
                              hipStream_t stream) {
    const float* x     = (const float*)d_in[0];
    const float* ea    = (const float*)d_in[1];
    const float* W1    = (const float*)d_in[2];
    const float* b1    = (const float*)d_in[3];
    const float* W2    = (const float*)d_in[4];
    const float* b2    = (const float*)d_in[5];
    const float* root  = (const float*)d_in[6];
    const float* bias1 = (const float*)d_in[7];
    const float* Wg    = (const float*)d_in[8];
    const float* bg    = (const float*)d_in[9];
    const int*   ei    = (const int*)d_in[10];
    float* out = (float*)d_out;

    // workspace layout (4-byte units; 16B-aligned segments)
    unsigned int* T = (unsigned int*)d_ws;            // 513*512 packed bf16x2
    float* tsort  = (float*)(T + 513 * 512);          // 512
    int*   ksort  = (int*)(tsort + 512);              // 512
    unsigned short* msgbuf = (unsigned short*)(ksort + 512); // E*32 bf16 (2.4M units)
    int*   deg    = (int*)((float*)msgbuf + 2400000); // N  <- memset to 0
    int*   offs   = deg + N_NODES;                    // N+4
    int*   rankm  = offs + N_NODES + 4;               // E
    int*   ssrc   = rankm + N_EDGES;                  // E
    float* xw12   = (float*)(ssrc + N_EDGES);         // N*12 (16B aligned)
    float* PbA    = xw12 + N_NODES * 12;              // 32*512
    float* PbB    = PbA + 32 * 512;
    float* SA     = PbB + 32 * 512;
    float* SB     = SA + 32 * 512;

    hipMemsetAsync(deg, 0, N_NODES * sizeof(int), stream);
    k1_rank<<<1, 512, 0, stream>>>(W1, b1, tsort, ksort);
    kb1_prep<<<(N_EDGES + 255) / 256, 256, 0, stream>>>(ei, ea, tsort, deg, rankm);
    s_scan<<<1, 1024, 0, stream>>>(deg, offs);
    p1_chunks<<<64, 256, 0, stream>>>(W1, b1, W2, ksort, PbA, PbB, SA, SB);
    p3s_emit<<<64, 256, 0, stream>>>(W1, b1, b2, W2, ksort, PbA, PbB, SA, SB, T);
    k3_edges<<<(N_EDGES * 32 + 255) / 256, 256, 0, stream>>>(x, ea, ei, rankm, offs,
                                                             T, msgbuf, ssrc);
    k4_nodes<<<(N_NODES + 255) / 256, 256, 0, stream>>>(x, offs,
                                                        (const unsigned int*)msgbuf,
                                                        root, bias1, Wg, xw12);
    k56_final<<<(N_NODES + 255) / 256, 256, 0, stream>>>(offs, ssrc, xw12, bg, out);
}

// Round 10
// 134.780 us; speedup vs baseline: 1.7321x; 1.0007x over previous
//
#include <hip/hip_runtime.h>
#include <math.h>

#define N_NODES 30000
#define N_EDGES 150000
#define IN_F 16
#define H_F 32
#define C_F 10
// K = IN*H = 512 hidden units in the edge MLP; 513 piecewise-linear intervals.
// theta(a) = a*A_m + B2_m on interval m. Tables packed: one uint32 per entry,
// hi16 = bf16(A), lo16 = bf16(B2), transposed layout T[m][o*16+i] so lane o
// reads its 32 weights as 4 uint4s (64B own line). k3 is L2-BW-bound on table
// reads; packing halves bytes/edge (4KB -> 2KB).
// NOTE: do NOT use hipMemsetAsync for small buffers — the rocclr fill kernel
// costs ~40us inside a captured graph (measured R9). Use k0_zero instead.

__device__ __forceinline__ unsigned bf16_rne(float f) {
    unsigned u = __float_as_uint(f);
    u += 0x7FFFu + ((u >> 16) & 1u);
    return u >> 16;
}

// ---------------------------------------------------------------------------
// K0: zero deg[N] (tiny, ~2us; replaces pathological hipMemsetAsync)
// ---------------------------------------------------------------------------
__global__ void k0_zero(int* __restrict__ p, int n) {
    int i = blockIdx.x * blockDim.x + threadIdx.x;
    int stride = gridDim.x * blockDim.x;
    for (; i < n; i += stride) p[i] = 0;
}

// ---------------------------------------------------------------------------
// K1: breakpoints t_k = -b1_k/W1_k, O(n^2) rank sort (no barriers in loop).
// ---------------------------------------------------------------------------
__global__ void k1_rank(const float* __restrict__ W1, const float* __restrict__ b1,
                        float* __restrict__ tsort, int* __restrict__ ksort) {
    __shared__ float st[512];
    int tid = threadIdx.x;
    float w = W1[tid], b = b1[tid];
    float t = (w != 0.0f) ? (-b / w) : 3.0e38f;
    st[tid] = t;
    __syncthreads();
    int rank = 0;
#pragma unroll 8
    for (int j = 0; j < 512; ++j) {
        float tj = st[j];
        rank += (tj < t || (tj == t && j < tid)) ? 1 : 0;
    }
    tsort[rank] = t;
    ksort[rank] = tid;
}

// ---------------------------------------------------------------------------
// KB1: per-edge prep: in-degree atomic (old value = rank within dst) +
// interval m via binary search; rankm[e] = rank<<10 | m.
// ---------------------------------------------------------------------------
__global__ void kb1_prep(const int* __restrict__ ei, const float* __restrict__ ea,
                         const float* __restrict__ tsort,
                         int* __restrict__ deg, int* __restrict__ rankm) {
    __shared__ float ts[512];
    for (int i = threadIdx.x; i < 512; i += blockDim.x) ts[i] = tsort[i];
    __syncthreads();
    int e = blockIdx.x * blockDim.x + threadIdx.x;
    if (e >= N_EDGES) return;
    int rank = atomicAdd(&deg[ei[N_EDGES + e]], 1);
    float a = ea[e];
    int lo = 0, hi = 512;
    while (lo < hi) {
        int mid = (lo + hi) >> 1;
        if (ts[mid] < a) lo = mid + 1; else hi = mid;
    }
    rankm[e] = (rank << 10) | lo;
}

// ---------------------------------------------------------------------------
// S_SCAN: single block, 1024 threads: exclusive scan of deg -> offs.
// ---------------------------------------------------------------------------
__global__ void s_scan(const int* __restrict__ deg, int* __restrict__ offs) {
    __shared__ int part[1024];
    int t = threadIdx.x;
    int base = t * 30;
    int loc[30];
    int s = 0;
#pragma unroll
    for (int i = 0; i < 30; ++i) {
        int idx = base + i;
        int v = (idx < N_NODES) ? deg[idx] : 0;
        loc[i] = v;
        s += v;
    }
    part[t] = s;
    __syncthreads();
    for (int off = 1; off < 1024; off <<= 1) {
        int v = part[t];
        int add = (t >= off) ? part[t - off] : 0;
        __syncthreads();
        part[t] = v + add;
        __syncthreads();
    }
    int run = (t > 0) ? part[t - 1] : 0;
#pragma unroll
    for (int i = 0; i < 30; ++i) {
        int idx = base + i;
        if (idx < N_NODES) offs[idx] = run;
        run += loc[i];
    }
    if (t == 1023) offs[N_NODES] = run;
}

// ---------------------------------------------------------------------------
// P1: per-chunk partial sums over 32 chunks of 16 ranks. Thread owns storage
// index jt (coalesced writes); W2 column jsrc = (jt&15)*32 + (jt>>4).
// ---------------------------------------------------------------------------
__global__ void p1_chunks(const float* __restrict__ W1, const float* __restrict__ b1,
                          const float* __restrict__ W2, const int* __restrict__ ksort,
                          float* __restrict__ PbA, float* __restrict__ PbB,
                          float* __restrict__ SA, float* __restrict__ SB) {
    int c = blockIdx.x & 31;
    int jc = blockIdx.x >> 5;
    int jt = jc * 256 + threadIdx.x;
    int jsrc = ((jt & 15) << 5) | (jt >> 4);
    float ba = 0.0f, bb = 0.0f, sa = 0.0f, sb = 0.0f;
#pragma unroll 4
    for (int s = 0; s < 16; ++s) {
        int k = c * 16 + s;
        float w = W1[k], b = b1[k];
        bool act = (w < 0.0f) || (w == 0.0f && b > 0.0f);
        if (act) {
            float w2 = W2[k * 512 + jsrc];
            ba = fmaf(w, w2, ba);
            bb = fmaf(b, w2, bb);
        }
        int kr = ksort[c * 16 + s];
        float wr = W1[kr], br = b1[kr];
        float sgn = (wr > 0.0f) ? 1.0f : ((wr < 0.0f) ? -1.0f : 0.0f);
        float w2r = W2[kr * 512 + jsrc];
        sa = fmaf(sgn * wr, w2r, sa);
        sb = fmaf(sgn * br, w2r, sb);
    }
    PbA[c * 512 + jt] = ba; PbB[c * 512 + jt] = bb;
    SA[c * 512 + jt] = sa;  SB[c * 512 + jt] = sb;
}

// ---------------------------------------------------------------------------
// P3S: fused scan + emit of PACKED table T[m*512+jt] = bf16(A)<<16|bf16(B2).
// Running sums stay f32; only the stored entries are bf16.
// ---------------------------------------------------------------------------
__global__ void p3s_emit(const float* __restrict__ W1, const float* __restrict__ b1,
                         const float* __restrict__ b2, const float* __restrict__ W2,
                         const int* __restrict__ ksort,
                         const float* __restrict__ PbA, const float* __restrict__ PbB,
                         const float* __restrict__ SA, const float* __restrict__ SB,
                         unsigned int* __restrict__ T) {
    int c = blockIdx.x & 31;
    int jc = blockIdx.x >> 5;
    int jt = jc * 256 + threadIdx.x;
    int jsrc = ((jt & 15) << 5) | (jt >> 4);
    float runA = 0.0f, runB = 0.0f;
#pragma unroll
    for (int c2 = 0; c2 < 32; ++c2) {
        runA += PbA[c2 * 512 + jt];
        runB += PbB[c2 * 512 + jt];
        if (c2 < c) { runA += SA[c2 * 512 + jt]; runB += SB[c2 * 512 + jt]; }
    }
    float bb2 = b2[jsrc];
#pragma unroll 4
    for (int s = 0; s < 16; ++s) {
        int m = c * 16 + s;
        T[m * 512 + jt] = (bf16_rne(runA) << 16) | bf16_rne(runB + bb2);
        int k = ksort[m];
        float w = W1[k], b = b1[k];
        float sgn = (w > 0.0f) ? 1.0f : ((w < 0.0f) ? -1.0f : 0.0f);
        float w2 = W2[k * 512 + jsrc];
        runA = fmaf(sgn * w, w2, runA);
        runB = fmaf(sgn * b, w2, runB);
    }
    if (c == 31) {
        T[512 * 512 + jt] = (bf16_rne(runA) << 16) | bf16_rne(runB + bb2);
    }
}

// ---------------------------------------------------------------------------
// K3: per-edge message, 32 lanes/edge. Lane o: 4 uint4 loads of packed
// (A,B2) weights; x broadcast via shfl from lanes 0..15; slot computed from
// offs[dst]+rank; bf16 store; lane 0 also fills ssrc[slot] (fused CSR fill).
// ---------------------------------------------------------------------------
__global__ void __launch_bounds__(256) k3_edges(
        const float* __restrict__ x, const float* __restrict__ ea,
        const int* __restrict__ ei, const int* __restrict__ rankm,
        const int* __restrict__ offs, const unsigned int* __restrict__ T,
        unsigned short* __restrict__ msgbuf, int* __restrict__ ssrc) {
    int gid = blockIdx.x * blockDim.x + threadIdx.x;
    int lane = gid & 31;
    int e = gid >> 5;
    if (e >= N_EDGES) return;
    float a = ea[e];
    int s = ei[e], d = ei[N_EDGES + e];
    int rm = rankm[e];
    int m = rm & 1023;
    int slot = offs[d] + (rm >> 10);
    const uint4* Tr = (const uint4*)(T + m * 512 + lane * 16);
    uint4 t0 = Tr[0], t1 = Tr[1], t2 = Tr[2], t3 = Tr[3];
    float xv = (lane < 16) ? x[s * 16 + lane] : 0.0f;
    float xa = 0.0f, xb = 0.0f;
    float xi;
#define STEP(w, i)                                                         \
    xi = __shfl(xv, i, 32);                                                \
    xa = fmaf(xi, __uint_as_float((w) & 0xFFFF0000u), xa);                 \
    xb = fmaf(xi, __uint_as_float((w) << 16), xb);
    STEP(t0.x, 0)  STEP(t0.y, 1)  STEP(t0.z, 2)  STEP(t0.w, 3)
    STEP(t1.x, 4)  STEP(t1.y, 5)  STEP(t1.z, 6)  STEP(t1.w, 7)
    STEP(t2.x, 8)  STEP(t2.y, 9)  STEP(t2.z, 10) STEP(t2.w, 11)
    STEP(t3.x, 12) STEP(t3.y, 13) STEP(t3.z, 14) STEP(t3.w, 15)
#undef STEP
    float msg = fmaf(a, xa, xb);
    unsigned int u = __float_as_uint(msg);
    u += 0x7FFFu + ((u >> 16) & 1u);
    msgbuf[slot * 32 + lane] = (unsigned short)(u >> 16);
    if (lane == 0) ssrc[slot] = s;
}

// ---------------------------------------------------------------------------
// K4: per-node: stream-sum contiguous msgbuf rows (bf16) -> aggr; h1 =
// relu(aggr/cnt + x@root + bias1); xw12[0..9] = h1@Wg; [10] = rsqrt(deg+1).
// ---------------------------------------------------------------------------
__global__ void k4_nodes(const float* __restrict__ x, const int* __restrict__ offs,
                         const unsigned int* __restrict__ msgbuf,
                         const float* __restrict__ root, const float* __restrict__ bias1,
                         const float* __restrict__ Wg,
                         float* __restrict__ xw12) {
    __shared__ float sroot[512], sb1[32], swg[320];
    for (int i = threadIdx.x; i < 512; i += blockDim.x) sroot[i] = root[i];
    for (int i = threadIdx.x; i < 32; i += blockDim.x) sb1[i] = bias1[i];
    for (int i = threadIdx.x; i < 320; i += blockDim.x) swg[i] = Wg[i];
    __syncthreads();
    int n = blockIdx.x * blockDim.x + threadIdx.x;
    if (n >= N_NODES) return;
    int s0 = offs[n], s1 = offs[n + 1];
    float agg[32];
#pragma unroll
    for (int o = 0; o < 32; ++o) agg[o] = 0.0f;
    for (int sl = s0; sl < s1; ++sl) {
        const uint4* rp = (const uint4*)(msgbuf + sl * 16);  // 64B row = 32 bf16
#pragma unroll
        for (int q = 0; q < 4; ++q) {
            uint4 v = rp[q];
            agg[q * 8 + 0] += __uint_as_float(v.x << 16);
            agg[q * 8 + 1] += __uint_as_float(v.x & 0xFFFF0000u);
            agg[q * 8 + 2] += __uint_as_float(v.y << 16);
            agg[q * 8 + 3] += __uint_as_float(v.y & 0xFFFF0000u);
            agg[q * 8 + 4] += __uint_as_float(v.z << 16);
            agg[q * 8 + 5] += __uint_as_float(v.z & 0xFFFF0000u);
            agg[q * 8 + 6] += __uint_as_float(v.w << 16);
            agg[q * 8 + 7] += __uint_as_float(v.w & 0xFFFF0000u);
        }
    }
    float c = (float)(s1 - s0);
    float inv = 1.0f / fmaxf(c, 1.0f);
    const float4* xp = (const float4*)(x + n * 16);
    float xr[16];
#pragma unroll
    for (int q = 0; q < 4; ++q) {
        float4 v = xp[q];
        xr[q * 4 + 0] = v.x; xr[q * 4 + 1] = v.y;
        xr[q * 4 + 2] = v.z; xr[q * 4 + 3] = v.w;
    }
    float acc[10];
#pragma unroll
    for (int cc = 0; cc < 10; ++cc) acc[cc] = 0.0f;
#pragma unroll
    for (int o = 0; o < 32; ++o) {
        float h = agg[o] * inv + sb1[o];
#pragma unroll
        for (int i = 0; i < 16; ++i) h = fmaf(xr[i], sroot[i * 32 + o], h);
        h = fmaxf(h, 0.0f);
#pragma unroll
        for (int cc = 0; cc < 10; ++cc) acc[cc] = fmaf(h, swg[o * 10 + cc], acc[cc]);
    }
    float4* op = (float4*)(xw12 + n * 12);
    op[0] = make_float4(acc[0], acc[1], acc[2], acc[3]);
    op[1] = make_float4(acc[4], acc[5], acc[6], acc[7]);
    op[2] = make_float4(acc[8], acc[9], rsqrtf(c + 1.0f), 0.0f);
}

// ---------------------------------------------------------------------------
// K56: fused GCN gather + self-loop + bias + log_softmax -> d_out.
// ---------------------------------------------------------------------------
__global__ void k56_final(const int* __restrict__ offs, const int* __restrict__ ssrc,
                          const float* __restrict__ xw12,
                          const float* __restrict__ bg, float* __restrict__ out) {
    __shared__ float sbg[16];
    if (threadIdx.x < 10) sbg[threadIdx.x] = bg[threadIdx.x];
    __syncthreads();
    int n = blockIdx.x * blockDim.x + threadIdx.x;
    if (n >= N_NODES) return;
    const float4* base = (const float4*)xw12;
    float4 r0 = base[n * 3], r1 = base[n * 3 + 1], r2 = base[n * 3 + 2];
    float dn = r2.z;
    float d2 = dn * dn;
    float acc[10];
    acc[0] = fmaf(r0.x, d2, sbg[0]); acc[1] = fmaf(r0.y, d2, sbg[1]);
    acc[2] = fmaf(r0.z, d2, sbg[2]); acc[3] = fmaf(r0.w, d2, sbg[3]);
    acc[4] = fmaf(r1.x, d2, sbg[4]); acc[5] = fmaf(r1.y, d2, sbg[5]);
    acc[6] = fmaf(r1.z, d2, sbg[6]); acc[7] = fmaf(r1.w, d2, sbg[7]);
    acc[8] = fmaf(r2.x, d2, sbg[8]); acc[9] = fmaf(r2.y, d2, sbg[9]);
    int s0 = offs[n], s1 = offs[n + 1];
    for (int sl = s0; sl < s1; ++sl) {
        int s = ssrc[sl];
        float4 q0 = base[s * 3], q1 = base[s * 3 + 1], q2 = base[s * 3 + 2];
        float nf = q2.z * dn;
        acc[0] = fmaf(q0.x, nf, acc[0]); acc[1] = fmaf(q0.y, nf, acc[1]);
        acc[2] = fmaf(q0.z, nf, acc[2]); acc[3] = fmaf(q0.w, nf, acc[3]);
        acc[4] = fmaf(q1.x, nf, acc[4]); acc[5] = fmaf(q1.y, nf, acc[5]);
        acc[6] = fmaf(q1.z, nf, acc[6]); acc[7] = fmaf(q1.w, nf, acc[7]);
        acc[8] = fmaf(q2.x, nf, acc[8]); acc[9] = fmaf(q2.y, nf, acc[9]);
    }
    float mx = -1e30f;
#pragma unroll
    for (int c = 0; c < 10; ++c) mx = fmaxf(mx, acc[c]);
    float se = 0.0f;
#pragma unroll
    for (int c = 0; c < 10; ++c) se += expf(acc[c] - mx);
    float lse = logf(se) + mx;
#pragma unroll
    for (int c = 0; c < 10; ++c) out[n * 10 + c] = acc[c] - lse;
}

// ---------------------------------------------------------------------------
extern "C" void kernel_launch(void* const* d_in, const int* in_sizes, int n_in,
                              void* d_out, int out_size, void* d_ws, size_t ws_size,
                              hipStream_t stream) {
    const float* x     = (const float*)d_in[0];
    const float* ea    = (const float*)d_in[1];
    const float* W1    = (const float*)d_in[2];
    const float* b1    = (const float*)d_in[3];
    const float* W2    = (const float*)d_in[4];
    const float* b2    = (const float*)d_in[5];
    const float* root  = (const float*)d_in[6];
    const float* bias1 = (const float*)d_in[7];
    const float* Wg    = (const float*)d_in[8];
    const float* bg    = (const float*)d_in[9];
    const int*   ei    = (const int*)d_in[10];
    float* out = (float*)d_out;

    // workspace layout (4-byte units; 16B-aligned segments)
    unsigned int* T = (unsigned int*)d_ws;            // 513*512 packed bf16x2
    float* tsort  = (float*)(T + 513 * 512);          // 512
    int*   ksort  = (int*)(tsort + 512);              // 512
    unsigned short* msgbuf = (unsigned short*)(ksort + 512); // E*32 bf16 (2.4M units)
    int*   deg    = (int*)((float*)msgbuf + 2400000); // N  <- zeroed by k0
    int*   offs   = deg + N_NODES;                    // N+4
    int*   rankm  = offs + N_NODES + 4;               // E
    int*   ssrc   = rankm + N_EDGES;                  // E
    float* xw12   = (float*)(ssrc + N_EDGES);         // N*12 (16B aligned)
    float* PbA    = xw12 + N_NODES * 12;              // 32*512
    float* PbB    = PbA + 32 * 512;
    float* SA     = PbB + 32 * 512;
    float* SB     = SA + 32 * 512;

    k0_zero<<<120, 256, 0, stream>>>(deg, N_NODES);
    k1_rank<<<1, 512, 0, stream>>>(W1, b1, tsort, ksort);
    kb1_prep<<<(N_EDGES + 255) / 256, 256, 0, stream>>>(ei, ea, tsort, deg, rankm);
    s_scan<<<1, 1024, 0, stream>>>(deg, offs);
    p1_chunks<<<64, 256, 0, stream>>>(W1, b1, W2, ksort, PbA, PbB, SA, SB);
    p3s_emit<<<64, 256, 0, stream>>>(W1, b1, b2, W2, ksort, PbA, PbB, SA, SB, T);
    k3_edges<<<(N_EDGES * 32 + 255) / 256, 256, 0, stream>>>(x, ea, ei, rankm, offs,
                                                             T, msgbuf, ssrc);
    k4_nodes<<<(N_NODES + 255) / 256, 256, 0, stream>>>(x, offs,
                                                        (const unsigned int*)msgbuf,
                                                        root, bias1, Wg, xw12);
    k56_final<<<(N_NODES + 255) / 256, 256, 0, stream>>>(offs, ssrc, xw12, bg, out);
}

// Round 11
// 109.392 us; speedup vs baseline: 2.1341x; 1.2321x over previous
//
#include <hip/hip_runtime.h>
#include <math.h>

#define N_NODES 30000
#define N_EDGES 150000
#define NB_E ((N_EDGES + 255) / 256)   // 586 edge-blocks in fused prep
// K = IN*H = 512 hidden units in the edge MLP; 513 piecewise-linear intervals.
// theta(a) = a*A_m + B2_m on interval m. Tables packed: one uint32 per entry,
// hi16 = bf16(A), lo16 = bf16(B2), transposed layout T[m][o*16+i] so lane o
// reads its 32 weights as 4 uint4s. Pipeline: k1z -> {kb1 || p1} ->
// {scan || p3s} -> k3(2 edges/group) -> k4 -> k56.  6 launches.
// NOTE: no hipMemsetAsync — rocclr fill kernel is pathological in-graph.

__device__ __forceinline__ unsigned bf16_rne(float f) {
    unsigned u = __float_as_uint(f);
    u += 0x7FFFu + ((u >> 16) & 1u);
    return u >> 16;
}

// ---------------------------------------------------------------------------
// K1Z: breakpoints t_k = -b1_k/W1_k, O(n^2) rank sort; then zero deg[N].
// 1 block x 512.
// ---------------------------------------------------------------------------
__global__ void k1z_rank(const float* __restrict__ W1, const float* __restrict__ b1,
                         float* __restrict__ tsort, int* __restrict__ ksort,
                         int* __restrict__ deg) {
    __shared__ float st[512];
    int tid = threadIdx.x;
    float w = W1[tid], b = b1[tid];
    float t = (w != 0.0f) ? (-b / w) : 3.0e38f;
    st[tid] = t;
    __syncthreads();
    int rank = 0;
#pragma unroll 8
    for (int j = 0; j < 512; ++j) {
        float tj = st[j];
        rank += (tj < t || (tj == t && j < tid)) ? 1 : 0;
    }
    tsort[rank] = t;
    ksort[rank] = tid;
    // zero deg (vector stores; kernel boundary orders it before f2's atomics)
    int4* dz = (int4*)deg;
    for (int i = tid; i < N_NODES / 4; i += 512) dz[i] = make_int4(0, 0, 0, 0);
}

// ---------------------------------------------------------------------------
// F2: fused independent pair.
// Blocks [0, NB_E): per-edge prep — in-degree atomic (old = rank within dst)
//   + interval m via binary search; rankm[e] = rank<<10 | m.
// Blocks [NB_E, NB_E+64): p1 chunk partial sums (32 chunks x 16 ranks);
//   thread owns storage index jt; W2 column jsrc = (jt&15)*32 + (jt>>4).
// ---------------------------------------------------------------------------
__global__ void __launch_bounds__(256) f2_prep(
        const int* __restrict__ ei, const float* __restrict__ ea,
        const float* __restrict__ tsort,
        int* __restrict__ deg, int* __restrict__ rankm,
        const float* __restrict__ W1, const float* __restrict__ b1,
        const float* __restrict__ W2, const int* __restrict__ ksort,
        float* __restrict__ PbA, float* __restrict__ PbB,
        float* __restrict__ SA, float* __restrict__ SB) {
    if (blockIdx.x < NB_E) {
        __shared__ float ts[512];
        for (int i = threadIdx.x; i < 512; i += 256) ts[i] = tsort[i];
        __syncthreads();
        int e = blockIdx.x * 256 + threadIdx.x;
        if (e >= N_EDGES) return;
        int rank = atomicAdd(&deg[ei[N_EDGES + e]], 1);
        float a = ea[e];
        int lo = 0, hi = 512;
        while (lo < hi) {
            int mid = (lo + hi) >> 1;
            if (ts[mid] < a) lo = mid + 1; else hi = mid;
        }
        rankm[e] = (rank << 10) | lo;
    } else {
        int bb = blockIdx.x - NB_E;
        int c = bb & 31;
        int jc = bb >> 5;
        int jt = jc * 256 + threadIdx.x;
        int jsrc = ((jt & 15) << 5) | (jt >> 4);
        float ba = 0.0f, bb2 = 0.0f, sa = 0.0f, sb = 0.0f;
#pragma unroll 4
        for (int s = 0; s < 16; ++s) {
            int k = c * 16 + s;
            float w = W1[k], b = b1[k];
            bool act = (w < 0.0f) || (w == 0.0f && b > 0.0f);
            if (act) {
                float w2 = W2[k * 512 + jsrc];
                ba = fmaf(w, w2, ba);
                bb2 = fmaf(b, w2, bb2);
            }
            int kr = ksort[c * 16 + s];
            float wr = W1[kr], br = b1[kr];
            float sgn = (wr > 0.0f) ? 1.0f : ((wr < 0.0f) ? -1.0f : 0.0f);
            float w2r = W2[kr * 512 + jsrc];
            sa = fmaf(sgn * wr, w2r, sa);
            sb = fmaf(sgn * br, w2r, sb);
        }
        PbA[c * 512 + jt] = ba; PbB[c * 512 + jt] = bb2;
        SA[c * 512 + jt] = sa;  SB[c * 512 + jt] = sb;
    }
}

// ---------------------------------------------------------------------------
// F3: fused independent pair, 1024 threads/block, grid 17.
// Block 0: exclusive scan of deg[30000] -> offs.
// Blocks 1..16: p3s table emit; c = (blk-1)*2 + (tid>>9), jt = tid&511.
// T[m*512+jt] = bf16(A)<<16 | bf16(B2) (running sums stay f32).
// ---------------------------------------------------------------------------
__global__ void __launch_bounds__(1024) f3_scan_emit(
        const int* __restrict__ deg, int* __restrict__ offs,
        const float* __restrict__ W1, const float* __restrict__ b1,
        const float* __restrict__ b2, const float* __restrict__ W2,
        const int* __restrict__ ksort,
        const float* __restrict__ PbA, const float* __restrict__ PbB,
        const float* __restrict__ SA, const float* __restrict__ SB,
        unsigned int* __restrict__ T) {
    __shared__ int part[1024];
    if (blockIdx.x == 0) {
        int t = threadIdx.x;
        int base = t * 30;
        int loc[30];
        int s = 0;
#pragma unroll
        for (int i = 0; i < 30; ++i) {
            int idx = base + i;
            int v = (idx < N_NODES) ? deg[idx] : 0;
            loc[i] = v;
            s += v;
        }
        part[t] = s;
        __syncthreads();
        for (int off = 1; off < 1024; off <<= 1) {
            int v = part[t];
            int add = (t >= off) ? part[t - off] : 0;
            __syncthreads();
            part[t] = v + add;
            __syncthreads();
        }
        int run = (t > 0) ? part[t - 1] : 0;
#pragma unroll
        for (int i = 0; i < 30; ++i) {
            int idx = base + i;
            if (idx < N_NODES) offs[idx] = run;
            run += loc[i];
        }
        if (t == 1023) offs[N_NODES] = run;
    } else {
        int c = (blockIdx.x - 1) * 2 + (threadIdx.x >> 9);
        int jt = threadIdx.x & 511;
        int jsrc = ((jt & 15) << 5) | (jt >> 4);
        float runA = 0.0f, runB = 0.0f;
#pragma unroll
        for (int c2 = 0; c2 < 32; ++c2) {
            runA += PbA[c2 * 512 + jt];
            runB += PbB[c2 * 512 + jt];
            if (c2 < c) { runA += SA[c2 * 512 + jt]; runB += SB[c2 * 512 + jt]; }
        }
        float bb2 = b2[jsrc];
#pragma unroll 4
        for (int s = 0; s < 16; ++s) {
            int m = c * 16 + s;
            T[m * 512 + jt] = (bf16_rne(runA) << 16) | bf16_rne(runB + bb2);
            int k = ksort[m];
            float w = W1[k], b = b1[k];
            float sgn = (w > 0.0f) ? 1.0f : ((w < 0.0f) ? -1.0f : 0.0f);
            float w2 = W2[k * 512 + jsrc];
            runA = fmaf(sgn * w, w2, runA);
            runB = fmaf(sgn * b, w2, runB);
        }
        if (c == 31) {
            T[512 * 512 + jt] = (bf16_rne(runA) << 16) | bf16_rne(runB + bb2);
        }
    }
}

// ---------------------------------------------------------------------------
// K3: TWO edges per 32-lane group (double memory-level parallelism; k3 is
// L2-latency-bound at VALUBusy ~13%). Metadata vectorized (float2/int2);
// 8 independent uint4 table loads in flight; interleaved FMA chains;
// bf16 stores to CSR slots; lane 0 fills ssrc for both edges.
// ---------------------------------------------------------------------------
__global__ void __launch_bounds__(256) k3_edges(
        const float* __restrict__ x, const float* __restrict__ ea,
        const int* __restrict__ ei, const int* __restrict__ rankm,
        const int* __restrict__ offs, const unsigned int* __restrict__ T,
        unsigned short* __restrict__ msgbuf, int* __restrict__ ssrc) {
    int gid = blockIdx.x * blockDim.x + threadIdx.x;
    int lane = gid & 31;
    int g = gid >> 5;
    int e0 = g << 1;
    if (e0 >= N_EDGES) return;
    float2 aa = *(const float2*)(ea + e0);
    int2 ss = *(const int2*)(ei + e0);
    int2 dd = *(const int2*)(ei + N_EDGES + e0);
    int2 rr = *(const int2*)(rankm + e0);
    int m0 = rr.x & 1023, m1 = rr.y & 1023;
    int slot0 = offs[dd.x] + (rr.x >> 10);
    int slot1 = offs[dd.y] + (rr.y >> 10);
    const uint4* T0 = (const uint4*)(T + m0 * 512 + lane * 16);
    const uint4* T1 = (const uint4*)(T + m1 * 512 + lane * 16);
    uint4 p0 = T0[0], p1 = T0[1], p2 = T0[2], p3 = T0[3];
    uint4 q0 = T1[0], q1 = T1[1], q2 = T1[2], q3 = T1[3];
    float xv0 = (lane < 16) ? x[ss.x * 16 + lane] : 0.0f;
    float xv1 = (lane < 16) ? x[ss.y * 16 + lane] : 0.0f;
    float xa0 = 0.0f, xb0 = 0.0f, xa1 = 0.0f, xb1 = 0.0f;
    float xi;
#define STEP2(w0, w1, i)                                                   \
    xi = __shfl(xv0, i, 32);                                               \
    xa0 = fmaf(xi, __uint_as_float((w0) & 0xFFFF0000u), xa0);              \
    xb0 = fmaf(xi, __uint_as_float((w0) << 16), xb0);                      \
    xi = __shfl(xv1, i, 32);                                               \
    xa1 = fmaf(xi, __uint_as_float((w1) & 0xFFFF0000u), xa1);              \
    xb1 = fmaf(xi, __uint_as_float((w1) << 16), xb1);
    STEP2(p0.x, q0.x, 0)  STEP2(p0.y, q0.y, 1)  STEP2(p0.z, q0.z, 2)  STEP2(p0.w, q0.w, 3)
    STEP2(p1.x, q1.x, 4)  STEP2(p1.y, q1.y, 5)  STEP2(p1.z, q1.z, 6)  STEP2(p1.w, q1.w, 7)
    STEP2(p2.x, q2.x, 8)  STEP2(p2.y, q2.y, 9)  STEP2(p2.z, q2.z, 10) STEP2(p2.w, q2.w, 11)
    STEP2(p3.x, q3.x, 12) STEP2(p3.y, q3.y, 13) STEP2(p3.z, q3.z, 14) STEP2(p3.w, q3.w, 15)
#undef STEP2
    float msg0 = fmaf(aa.x, xa0, xb0);
    float msg1 = fmaf(aa.y, xa1, xb1);
    msgbuf[slot0 * 32 + lane] = (unsigned short)bf16_rne(msg0);
    msgbuf[slot1 * 32 + lane] = (unsigned short)bf16_rne(msg1);
    if (lane == 0) { ssrc[slot0] = ss.x; ssrc[slot1] = ss.y; }
}

// ---------------------------------------------------------------------------
// K4: per-node: stream-sum contiguous msgbuf rows (bf16) -> aggr; h1 =
// relu(aggr/cnt + x@root + bias1); xw12[0..9] = h1@Wg; [10] = rsqrt(deg+1).
// ---------------------------------------------------------------------------
__global__ void k4_nodes(const float* __restrict__ x, const int* __restrict__ offs,
                         const unsigned int* __restrict__ msgbuf,
                         const float* __restrict__ root, const float* __restrict__ bias1,
                         const float* __restrict__ Wg,
                         float* __restrict__ xw12) {
    __shared__ float sroot[512], sb1[32], swg[320];
    for (int i = threadIdx.x; i < 512; i += blockDim.x) sroot[i] = root[i];
    for (int i = threadIdx.x; i < 32; i += blockDim.x) sb1[i] = bias1[i];
    for (int i = threadIdx.x; i < 320; i += blockDim.x) swg[i] = Wg[i];
    __syncthreads();
    int n = blockIdx.x * blockDim.x + threadIdx.x;
    if (n >= N_NODES) return;
    int s0 = offs[n], s1 = offs[n + 1];
    float agg[32];
#pragma unroll
    for (int o = 0; o < 32; ++o) agg[o] = 0.0f;
    for (int sl = s0; sl < s1; ++sl) {
        const uint4* rp = (const uint4*)(msgbuf + sl * 16);  // 64B row = 32 bf16
#pragma unroll
        for (int q = 0; q < 4; ++q) {
            uint4 v = rp[q];
            agg[q * 8 + 0] += __uint_as_float(v.x << 16);
            agg[q * 8 + 1] += __uint_as_float(v.x & 0xFFFF0000u);
            agg[q * 8 + 2] += __uint_as_float(v.y << 16);
            agg[q * 8 + 3] += __uint_as_float(v.y & 0xFFFF0000u);
            agg[q * 8 + 4] += __uint_as_float(v.z << 16);
            agg[q * 8 + 5] += __uint_as_float(v.z & 0xFFFF0000u);
            agg[q * 8 + 6] += __uint_as_float(v.w << 16);
            agg[q * 8 + 7] += __uint_as_float(v.w & 0xFFFF0000u);
        }
    }
    float c = (float)(s1 - s0);
    float inv = 1.0f / fmaxf(c, 1.0f);
    const float4* xp = (const float4*)(x + n * 16);
    float xr[16];
#pragma unroll
    for (int q = 0; q < 4; ++q) {
        float4 v = xp[q];
        xr[q * 4 + 0] = v.x; xr[q * 4 + 1] = v.y;
        xr[q * 4 + 2] = v.z; xr[q * 4 + 3] = v.w;
    }
    float acc[10];
#pragma unroll
    for (int cc = 0; cc < 10; ++cc) acc[cc] = 0.0f;
#pragma unroll
    for (int o = 0; o < 32; ++o) {
        float h = agg[o] * inv + sb1[o];
#pragma unroll
        for (int i = 0; i < 16; ++i) h = fmaf(xr[i], sroot[i * 32 + o], h);
        h = fmaxf(h, 0.0f);
#pragma unroll
        for (int cc = 0; cc < 10; ++cc) acc[cc] = fmaf(h, swg[o * 10 + cc], acc[cc]);
    }
    float4* op = (float4*)(xw12 + n * 12);
    op[0] = make_float4(acc[0], acc[1], acc[2], acc[3]);
    op[1] = make_float4(acc[4], acc[5], acc[6], acc[7]);
    op[2] = make_float4(acc[8], acc[9], rsqrtf(c + 1.0f), 0.0f);
}

// ---------------------------------------------------------------------------
// K56: fused GCN gather + self-loop + bias + log_softmax -> d_out.
// ---------------------------------------------------------------------------
__global__ void k56_final(const int* __restrict__ offs, const int* __restrict__ ssrc,
                          const float* __restrict__ xw12,
                          const float* __restrict__ bg, float* __restrict__ out) {
    __shared__ float sbg[16];
    if (threadIdx.x < 10) sbg[threadIdx.x] = bg[threadIdx.x];
    __syncthreads();
    int n = blockIdx.x * blockDim.x + threadIdx.x;
    if (n >= N_NODES) return;
    const float4* base = (const float4*)xw12;
    float4 r0 = base[n * 3], r1 = base[n * 3 + 1], r2 = base[n * 3 + 2];
    float dn = r2.z;
    float d2 = dn * dn;
    float acc[10];
    acc[0] = fmaf(r0.x, d2, sbg[0]); acc[1] = fmaf(r0.y, d2, sbg[1]);
    acc[2] = fmaf(r0.z, d2, sbg[2]); acc[3] = fmaf(r0.w, d2, sbg[3]);
    acc[4] = fmaf(r1.x, d2, sbg[4]); acc[5] = fmaf(r1.y, d2, sbg[5]);
    acc[6] = fmaf(r1.z, d2, sbg[6]); acc[7] = fmaf(r1.w, d2, sbg[7]);
    acc[8] = fmaf(r2.x, d2, sbg[8]); acc[9] = fmaf(r2.y, d2, sbg[9]);
    int s0 = offs[n], s1 = offs[n + 1];
    for (int sl = s0; sl < s1; ++sl) {
        int s = ssrc[sl];
        float4 q0 = base[s * 3], q1 = base[s * 3 + 1], q2 = base[s * 3 + 2];
        float nf = q2.z * dn;
        acc[0] = fmaf(q0.x, nf, acc[0]); acc[1] = fmaf(q0.y, nf, acc[1]);
        acc[2] = fmaf(q0.z, nf, acc[2]); acc[3] = fmaf(q0.w, nf, acc[3]);
        acc[4] = fmaf(q1.x, nf, acc[4]); acc[5] = fmaf(q1.y, nf, acc[5]);
        acc[6] = fmaf(q1.z, nf, acc[6]); acc[7] = fmaf(q1.w, nf, acc[7]);
        acc[8] = fmaf(q2.x, nf, acc[8]); acc[9] = fmaf(q2.y, nf, acc[9]);
    }
    float mx = -1e30f;
#pragma unroll
    for (int c = 0; c < 10; ++c) mx = fmaxf(mx, acc[c]);
    float se = 0.0f;
#pragma unroll
    for (int c = 0; c < 10; ++c) se += expf(acc[c] - mx);
    float lse = logf(se) + mx;
#pragma unroll
    for (int c = 0; c < 10; ++c) out[n * 10 + c] = acc[c] - lse;
}

// ---------------------------------------------------------------------------
extern "C" void kernel_launch(void* const* d_in, const int* in_sizes, int n_in,
                              void* d_out, int out_size, void* d_ws, size_t ws_size,
                              hipStream_t stream) {
    const float* x     = (const float*)d_in[0];
    const float* ea    = (const float*)d_in[1];
    const float* W1    = (const float*)d_in[2];
    const float* b1    = (const float*)d_in[3];
    const float* W2    = (const float*)d_in[4];
    const float* b2    = (const float*)d_in[5];
    const float* root  = (const float*)d_in[6];
    const float* bias1 = (const float*)d_in[7];
    const float* Wg    = (const float*)d_in[8];
    const float* bg    = (const float*)d_in[9];
    const int*   ei    = (const int*)d_in[10];
    float* out = (float*)d_out;

    // workspace layout (4-byte units; 16B-aligned segments)
    unsigned int* T = (unsigned int*)d_ws;            // 513*512 packed bf16x2
    float* tsort  = (float*)(T + 513 * 512);          // 512
    int*   ksort  = (int*)(tsort + 512);              // 512
    unsigned short* msgbuf = (unsigned short*)(ksort + 512); // E*32 bf16 (2.4M units)
    int*   deg    = (int*)((float*)msgbuf + 2400000); // N  <- zeroed in k1z
    int*   offs   = deg + N_NODES;                    // N+4
    int*   rankm  = offs + N_NODES + 4;               // E
    int*   ssrc   = rankm + N_EDGES;                  // E
    float* xw12   = (float*)(ssrc + N_EDGES);         // N*12 (16B aligned)
    float* PbA    = xw12 + N_NODES * 12;              // 32*512
    float* PbB    = PbA + 32 * 512;
    float* SA     = PbB + 32 * 512;
    float* SB     = SA + 32 * 512;

    k1z_rank<<<1, 512, 0, stream>>>(W1, b1, tsort, ksort, deg);
    f2_prep<<<NB_E + 64, 256, 0, stream>>>(ei, ea, tsort, deg, rankm,
                                           W1, b1, W2, ksort, PbA, PbB, SA, SB);
    f3_scan_emit<<<17, 1024, 0, stream>>>(deg, offs, W1, b1, b2, W2, ksort,
                                          PbA, PbB, SA, SB, T);
    k3_edges<<<(N_EDGES / 2 * 32 + 255) / 256, 256, 0, stream>>>(
        x, ea, ei, rankm, offs, T, msgbuf, ssrc);
    k4_nodes<<<(N_NODES + 255) / 256, 256, 0, stream>>>(x, offs,
                                                        (const unsigned int*)msgbuf,
                                                        root, bias1, Wg, xw12);
    k56_final<<<(N_NODES + 255) / 256, 256, 0, stream>>>(offs, ssrc, xw12, bg, out);
}